// Round 6
// baseline (303.222 us; speedup 1.0000x reference)
//
#include <hip/hip_runtime.h>
#include <cstdint>
#include <cstddef>

#define GLOBAL_AS __attribute__((address_space(1)))
#define LDS_AS __attribute__((address_space(3)))

typedef __attribute__((ext_vector_type(8))) short short8;
typedef __attribute__((ext_vector_type(4))) float floatx4;
typedef __attribute__((ext_vector_type(2))) long long2v;   // 16B LDS read

#if defined(__has_builtin)
#if __has_builtin(__builtin_amdgcn_cvt_pk_fp8_f32)
#define HAVE_HW_FP8 1
#endif
#endif

static __device__ __forceinline__ unsigned short f2bf(float f) {
  uint32_t u = __builtin_bit_cast(uint32_t, f);
  u += 0x7fffu + ((u >> 16) & 1u);
  return (unsigned short)(u >> 16);
}

// OCP e4m3 encode (RNE, saturate to 448)
static __device__ __forceinline__ unsigned char f2fp8(float f) {
#ifdef HAVE_HW_FP8
  float c = fminf(fmaxf(f, -448.f), 448.f);
  return (unsigned char)(__builtin_amdgcn_cvt_pk_fp8_f32(c, 0.f, 0, false) & 0xff);
#else
  unsigned char s = 0;
  if (f < 0.f) { s = 0x80; f = -f; }
  if (f >= 448.f) return s | 0x7e;
  if (f < 0.015625f) { int r = (int)(f * 512.f + 0.5f); return s | (unsigned char)r; }
  uint32_t u = __builtin_bit_cast(uint32_t, f);
  int e = (int)((u >> 23) & 0xff) - 127;
  uint32_t keep = (u >> 20) & 7, rest = u & 0xfffffu;
  if (rest > 0x80000u || (rest == 0x80000u && (keep & 1))) ++keep;
  if (keep == 8) { keep = 0; ++e; }
  if (e > 8) return s | 0x7e;
  return s | (unsigned char)(((e + 7) << 3) | keep);
#endif
}

static __device__ __forceinline__ void wait_vm0() {
  // vmcnt(0), expcnt/lgkmcnt unconstrained
  __builtin_amdgcn_s_waitcnt(0x0f70);
}

// ---------------------------------------------------------------------------
// Transpose H: fp32 [R][C] -> HbT8 fp8 [C][R], plus straight bf16 copy [R][C]
// ---------------------------------------------------------------------------
__global__ __launch_bounds__(256) void transpose_h_kernel(
    const float* __restrict__ in, unsigned char* __restrict__ outT8,
    unsigned short* __restrict__ outN, int R, int C) {
  __shared__ float t[64][65];
  const int bc = blockIdx.x * 64;
  const int br = blockIdx.y * 64;
  const int tc = threadIdx.x & 63;
  const int tr = threadIdx.x >> 6;
  for (int r = tr; r < 64; r += 4) {
    const float v = in[(size_t)(br + r) * C + bc + tc];
    t[r][tc] = v;
    outN[(size_t)(br + r) * C + bc + tc] = f2bf(v);
  }
  __syncthreads();
  for (int r = tr; r < 64; r += 4)
    outT8[(size_t)(bc + r) * R + br + tc] = f2fp8(t[tc][r]);
}

// Transpose weights: fp32 [R][C] -> bf16 [C][R]
__global__ __launch_bounds__(256) void transpose_w_kernel(
    const float* __restrict__ in, unsigned short* __restrict__ outT, int R, int C) {
  __shared__ float t[64][65];
  const int bc = blockIdx.x * 64;
  const int br = blockIdx.y * 64;
  const int tc = threadIdx.x & 63;
  const int tr = threadIdx.x >> 6;
  for (int r = tr; r < 64; r += 4)
    t[r][tc] = in[(size_t)(br + r) * C + bc + tc];
  __syncthreads();
  for (int r = tr; r < 64; r += 4)
    outT[(size_t)(bc + r) * R + br + tc] = f2bf(t[tc][r]);
}

__global__ __launch_bounds__(256) void pack_bias_kernel(
    const float* __restrict__ bq, const float* __restrict__ bk,
    float* __restrict__ bqk) {
  int i = blockIdx.x * 256 + threadIdx.x;
  bqk[i] = (i < 512) ? bq[i] : bk[i - 512];
}

// ---------------------------------------------------------------------------
// Projection GEMM (bf16 x bf16 -> fp8): QK8[m][n] = fp8(A[m][k]*Bt[n][k]+b[n])
// 128x128 tile, BK=32, double-buffered one-barrier K-loop.
// ---------------------------------------------------------------------------
__global__ __launch_bounds__(256, 4) void gemm_proj(
    const unsigned short* __restrict__ A,    // Hb [8192][512] bf16
    const unsigned short* __restrict__ Bt,   // BqkT [1024][512] bf16
    int Ncols, int K,
    const float* __restrict__ bias,
    unsigned char* __restrict__ C8)          // QK8 [8192][1024] fp8
{
  __shared__ unsigned short As[2][128 * 32];
  __shared__ unsigned short Bs[2][128 * 32];

  const int tid  = threadIdx.x;
  const int lane = tid & 63;
  const int wave = tid >> 6;
  const int wr   = (wave >> 1) * 64;
  const int wc   = (wave & 1) * 64;
  const int quad = lane >> 4;
  const int l15  = lane & 15;
  const int bm   = blockIdx.y * 128;
  const int bn   = blockIdx.x * 128;

  const int c0 = tid, c1 = tid + 256;
  const int r0a = c0 >> 2, k0a = (c0 & 3) << 3;
  const int r1a = c1 >> 2, k1a = (c1 & 3) << 3;

  auto stage = [&](int kt, int b) {
    __builtin_amdgcn_global_load_lds(
        (const GLOBAL_AS void*)(A + (size_t)(bm + r0a) * K + kt + k0a),
        (LDS_AS void*)(&As[b][c0 * 8]), 16, 0, 0);
    __builtin_amdgcn_global_load_lds(
        (const GLOBAL_AS void*)(A + (size_t)(bm + r1a) * K + kt + k1a),
        (LDS_AS void*)(&As[b][c1 * 8]), 16, 0, 0);
    __builtin_amdgcn_global_load_lds(
        (const GLOBAL_AS void*)(Bt + (size_t)(bn + r0a) * K + kt + k0a),
        (LDS_AS void*)(&Bs[b][c0 * 8]), 16, 0, 0);
    __builtin_amdgcn_global_load_lds(
        (const GLOBAL_AS void*)(Bt + (size_t)(bn + r1a) * K + kt + k1a),
        (LDS_AS void*)(&Bs[b][c1 * 8]), 16, 0, 0);
  };

  floatx4 acc[4][4];
#pragma unroll
  for (int i = 0; i < 4; ++i)
#pragma unroll
    for (int j = 0; j < 4; ++j)
      acc[i][j] = (floatx4){0.f, 0.f, 0.f, 0.f};

  stage(0, 0);
  const int nIter = K >> 5;
  for (int it = 0; it < nIter; ++it) {
    const int b = it & 1;
    wait_vm0();
    __syncthreads();
    if (it + 1 < nIter) stage((it + 1) << 5, b ^ 1);

    short8 af[4], bfr[4];
#pragma unroll
    for (int i = 0; i < 4; ++i)
      af[i] = *(const short8*)(&As[b][(wr + i * 16 + l15) * 32 + quad * 8]);
#pragma unroll
    for (int j = 0; j < 4; ++j)
      bfr[j] = *(const short8*)(&Bs[b][(wc + j * 16 + l15) * 32 + quad * 8]);
#pragma unroll
    for (int i = 0; i < 4; ++i)
#pragma unroll
      for (int j = 0; j < 4; ++j)
        acc[i][j] = __builtin_amdgcn_mfma_f32_16x16x32_bf16(af[i], bfr[j], acc[i][j], 0, 0, 0);
  }

  // epilogue — C/D layout: col = lane&15, row = quad*4 + reg
#pragma unroll
  for (int i = 0; i < 4; ++i) {
    const int rl = bm + wr + i * 16 + quad * 4;
#pragma unroll
    for (int r = 0; r < 4; ++r) {
      const int row = rl + r;
#pragma unroll
      for (int j = 0; j < 4; ++j) {
        const int col = bn + wc + j * 16 + l15;
        C8[(size_t)row * Ncols + col] = f2fp8(acc[i][j][r] + bias[col]);
      }
    }
  }
}

// ---------------------------------------------------------------------------
// Scores GEMM fp8 x fp8: P8 = fp8(exp(diag0(Q K^T)*scale)), fused row-sums.
// 128x128 tile, BK=64, double-buffered one-barrier loop.
// K-permutation trick: mfma call t, quad q covers global k = q*16 + t*8 + j,
// so each lane's two 8B fragments are one contiguous 16B ds_read_b128 at
// row*64 + quad*16 (bank pattern identical to the proven bf16 layout).
// (256,5): LDS 32KB x5 = 160KB exactly; VGPR cap 102 (have 56).
// ---------------------------------------------------------------------------
__global__ __launch_bounds__(256, 5) void gemm_qk8(
    const unsigned char* __restrict__ A,     // Q8 rows [.][lda] fp8
    const unsigned char* __restrict__ Bt,    // K8 [8192][ldb] fp8
    int Ncols, int K, int lda, int ldb,
    float* __restrict__ lsum,
    int row0,
    unsigned char* __restrict__ P8)
{
  __shared__ unsigned char As[2][128 * 64];   // 8 KiB x2
  __shared__ unsigned char Bs[2][128 * 64];   // 8 KiB x2

  const int tid  = threadIdx.x;
  const int lane = tid & 63;
  const int wave = tid >> 6;
  const int wr   = (wave >> 1) * 64;
  const int wc   = (wave & 1) * 64;
  const int quad = lane >> 4;
  const int l15  = lane & 15;
  const int bm   = blockIdx.y * 128;
  const int bn   = blockIdx.x * 128;

  // staging: 512 chunks of 16B cover 128 rows x 64B; c -> row c>>2, kofs (c&3)*16
  const int c0 = tid, c1 = tid + 256;
  const int r0a = c0 >> 2, k0a = (c0 & 3) << 4;
  const int r1a = c1 >> 2, k1a = (c1 & 3) << 4;

  auto stage = [&](int kt, int b) {
    __builtin_amdgcn_global_load_lds(
        (const GLOBAL_AS void*)(A + (size_t)(bm + r0a) * lda + kt + k0a),
        (LDS_AS void*)(&As[b][c0 * 16]), 16, 0, 0);
    __builtin_amdgcn_global_load_lds(
        (const GLOBAL_AS void*)(A + (size_t)(bm + r1a) * lda + kt + k1a),
        (LDS_AS void*)(&As[b][c1 * 16]), 16, 0, 0);
    __builtin_amdgcn_global_load_lds(
        (const GLOBAL_AS void*)(Bt + (size_t)(bn + r0a) * ldb + kt + k0a),
        (LDS_AS void*)(&Bs[b][c0 * 16]), 16, 0, 0);
    __builtin_amdgcn_global_load_lds(
        (const GLOBAL_AS void*)(Bt + (size_t)(bn + r1a) * ldb + kt + k1a),
        (LDS_AS void*)(&Bs[b][c1 * 16]), 16, 0, 0);
  };

  floatx4 acc[4][4];
#pragma unroll
  for (int i = 0; i < 4; ++i)
#pragma unroll
    for (int j = 0; j < 4; ++j)
      acc[i][j] = (floatx4){0.f, 0.f, 0.f, 0.f};

  stage(0, 0);
  const int nIter = K >> 6;
  for (int it = 0; it < nIter; ++it) {
    const int b = it & 1;
    wait_vm0();
    __syncthreads();
    if (it + 1 < nIter) stage((it + 1) << 6, b ^ 1);

    long2v af[4], bfr[4];
#pragma unroll
    for (int i = 0; i < 4; ++i)
      af[i] = *(const long2v*)(&As[b][(wr + i * 16 + l15) * 64 + quad * 16]);
#pragma unroll
    for (int j = 0; j < 4; ++j)
      bfr[j] = *(const long2v*)(&Bs[b][(wc + j * 16 + l15) * 64 + quad * 16]);
#pragma unroll
    for (int i = 0; i < 4; ++i)
#pragma unroll
      for (int j = 0; j < 4; ++j) {
        acc[i][j] = __builtin_amdgcn_mfma_f32_16x16x32_fp8_fp8(af[i].x, bfr[j].x, acc[i][j], 0, 0, 0);
        acc[i][j] = __builtin_amdgcn_mfma_f32_16x16x32_fp8_fp8(af[i].y, bfr[j].y, acc[i][j], 0, 0, 0);
      }
  }

  const float scale = 0.044194173824159216f;  // 1/sqrt(512)
#pragma unroll
  for (int i = 0; i < 4; ++i) {
    const int rl = bm + wr + i * 16 + quad * 4;
#pragma unroll
    for (int r = 0; r < 4; ++r) {
      const int row = rl + r;
      float e[4];
#pragma unroll
      for (int j = 0; j < 4; ++j) {
        const int col = bn + wc + j * 16 + l15;
        const float lg = ((row0 + row) == col) ? 0.f : acc[i][j][r] * scale;
        e[j] = fminf(__expf(lg), 448.f);
      }
      // row-sum from the fp32 values (pre-quantization): the fp8 num/denom
      // inconsistency is ~0.004% relative on l — far below threshold.
      float rsum = (e[0] + e[1]) + (e[2] + e[3]);
      const size_t rb = (size_t)row * Ncols + bn + wc + l15;
#ifdef HAVE_HW_FP8
      const int p01 = __builtin_amdgcn_cvt_pk_fp8_f32(e[0], e[1], 0, false);
      const int p23 = __builtin_amdgcn_cvt_pk_fp8_f32(e[2], e[3], 0, false);
      P8[rb]      = (unsigned char)(p01 & 0xff);
      P8[rb + 16] = (unsigned char)((p01 >> 8) & 0xff);
      P8[rb + 32] = (unsigned char)(p23 & 0xff);
      P8[rb + 48] = (unsigned char)((p23 >> 8) & 0xff);
#else
      P8[rb]      = f2fp8(e[0]);
      P8[rb + 16] = f2fp8(e[1]);
      P8[rb + 32] = f2fp8(e[2]);
      P8[rb + 48] = f2fp8(e[3]);
#endif
      rsum += __shfl_xor(rsum, 1);
      rsum += __shfl_xor(rsum, 2);
      rsum += __shfl_xor(rsum, 4);
      rsum += __shfl_xor(rsum, 8);
      if (l15 == 0) atomicAdd(&lsum[row0 + row], rsum);
    }
  }
}

// ---------------------------------------------------------------------------
// PV GEMM fp8 x fp8: O[m][n] = sum_k P8[m][k]*HbT8[n][k]. 64x128 tile, BK=64,
// double-buffered, split-K over z. Same K-permutation b128 trick as gemm_qk8.
// (256,6): LDS 24KB x6 = 144KB; VGPR cap 85 (have 40).
// ---------------------------------------------------------------------------
template <bool DIRECT>
__global__ __launch_bounds__(256, 6) void gemm_pv8(
    const unsigned char* __restrict__ P,     // [rows][8192] fp8 (chunk base)
    const unsigned char* __restrict__ Bt,    // HbT8 [512][8192] fp8
    int Kchunk,
    const float* __restrict__ lvec,
    const float* __restrict__ Hres,
    int row0,
    float* __restrict__ outp,
    size_t partStride)
{
  __shared__ unsigned char As[2][64 * 64];    // 4 KiB x2
  __shared__ unsigned char Bs[2][128 * 64];   // 8 KiB x2

  const int tid  = threadIdx.x;
  const int lane = tid & 63;
  const int wave = tid >> 6;
  const int wr   = (wave >> 1) * 32;
  const int wc   = (wave & 1) * 64;
  const int quad = lane >> 4;
  const int l15  = lane & 15;
  const int bm   = blockIdx.y * 64;
  const int bn   = blockIdx.x * 128;
  const int k0   = blockIdx.z * Kchunk;

  float* part = outp + (DIRECT ? 0 : (size_t)blockIdx.z * partStride);

  const int rA = tid >> 2,  kA = (tid & 3) << 4;    // 256 chunks: 64 rows x 64B
  const int cB1 = tid + 256;
  const int rB0 = tid >> 2, kB0 = (tid & 3) << 4;   // 512 chunks: 128 rows x 64B
  const int rB1 = cB1 >> 2, kB1 = (cB1 & 3) << 4;

  auto stage = [&](int kt, int b) {
    __builtin_amdgcn_global_load_lds(
        (const GLOBAL_AS void*)(P + (size_t)(bm + rA) * 8192 + kt + kA),
        (LDS_AS void*)(&As[b][tid * 16]), 16, 0, 0);
    __builtin_amdgcn_global_load_lds(
        (const GLOBAL_AS void*)(Bt + (size_t)(bn + rB0) * 8192 + kt + kB0),
        (LDS_AS void*)(&Bs[b][tid * 16]), 16, 0, 0);
    __builtin_amdgcn_global_load_lds(
        (const GLOBAL_AS void*)(Bt + (size_t)(bn + rB1) * 8192 + kt + kB1),
        (LDS_AS void*)(&Bs[b][cB1 * 16]), 16, 0, 0);
  };

  floatx4 acc[2][4];
#pragma unroll
  for (int i = 0; i < 2; ++i)
#pragma unroll
    for (int j = 0; j < 4; ++j)
      acc[i][j] = (floatx4){0.f, 0.f, 0.f, 0.f};

  stage(k0, 0);
  const int nIter = Kchunk >> 6;
  for (int it = 0; it < nIter; ++it) {
    const int b = it & 1;
    wait_vm0();
    __syncthreads();
    if (it + 1 < nIter) stage(k0 + ((it + 1) << 6), b ^ 1);

    long2v af[2], bfr[4];
#pragma unroll
    for (int i = 0; i < 2; ++i)
      af[i] = *(const long2v*)(&As[b][(wr + i * 16 + l15) * 64 + quad * 16]);
#pragma unroll
    for (int j = 0; j < 4; ++j)
      bfr[j] = *(const long2v*)(&Bs[b][(wc + j * 16 + l15) * 64 + quad * 16]);
#pragma unroll
    for (int i = 0; i < 2; ++i)
#pragma unroll
      for (int j = 0; j < 4; ++j) {
        acc[i][j] = __builtin_amdgcn_mfma_f32_16x16x32_fp8_fp8(af[i].x, bfr[j].x, acc[i][j], 0, 0, 0);
        acc[i][j] = __builtin_amdgcn_mfma_f32_16x16x32_fp8_fp8(af[i].y, bfr[j].y, acc[i][j], 0, 0, 0);
      }
  }

#pragma unroll
  for (int i = 0; i < 2; ++i) {
    const int rl = bm + wr + i * 16 + quad * 4;
#pragma unroll
    for (int j = 0; j < 4; ++j) {
      const int col = bn + wc + j * 16 + l15;
#pragma unroll
      for (int r = 0; r < 4; ++r) {
        const int row = rl + r;
        const float v = acc[i][j][r];
        if (DIRECT) {
          const int grow = row0 + row;
          part[(size_t)grow * 512 + col] =
              v / lvec[grow] + Hres[(size_t)grow * 512 + col];
        } else {
          part[(size_t)row * 512 + col] = v;
        }
      }
    }
  }
}

// combine: out = (sum_s partial_s) / l[row] + H
__global__ __launch_bounds__(256) void combine_kernel(
    const float* __restrict__ parts, size_t partStride, int S,
    const float* __restrict__ lvec, const float* __restrict__ Hres,
    float* __restrict__ out, int n4) {
  int i = blockIdx.x * 256 + threadIdx.x;
  if (i >= n4) return;
  float4 a = ((const float4*)parts)[i];
  for (int s = 1; s < S; ++s) {
    const float4 b = ((const float4*)(parts + (size_t)s * partStride))[i];
    a.x += b.x; a.y += b.y; a.z += b.z; a.w += b.w;
  }
  const int row = i >> 7;
  const float inv = 1.f / lvec[row];
  const float4 h = ((const float4*)Hres)[i];
  float4 o;
  o.x = a.x * inv + h.x;
  o.y = a.y * inv + h.y;
  o.z = a.z * inv + h.z;
  o.w = a.w * inv + h.w;
  ((float4*)out)[i] = o;
}

// ---------------------------------------------------------------------------
extern "C" void kernel_launch(void* const* d_in, const int* in_sizes, int n_in,
                              void* d_out, int out_size, void* d_ws, size_t ws_size,
                              hipStream_t stream) {
  const float* H  = (const float*)d_in[0];
  const float* Wq = (const float*)d_in[1];
  const float* bq = (const float*)d_in[2];
  const float* Wk = (const float*)d_in[3];
  const float* bk = (const float*)d_in[4];
  float* out = (float*)d_out;

  const int N = 8192, D = 512;

  char* ws = (char*)d_ws;
  size_t off = 0;
  auto alloc = [&](size_t bytes) { char* p = ws + off; off += bytes; return p; };
  unsigned short* Hb   = (unsigned short*)alloc((size_t)N * D * 2);       // 8 MB
  unsigned char*  HbT8 = (unsigned char*)alloc((size_t)D * N);            // 4.2 MB
  unsigned char*  QK8  = (unsigned char*)alloc((size_t)N * 2 * D);        // 8.4 MB
  unsigned short* BqkT = (unsigned short*)alloc((size_t)2 * D * D * 2);   // 1 MB
  float* bqk = (float*)alloc((size_t)2 * D * 4);
  float* l   = (float*)alloc((size_t)N * 4);
  const size_t base = off;
  unsigned char* P8 = (unsigned char*)(ws + base);

  const size_t pBytes = (size_t)N * N;                   // 67 MB (fp8)
  const size_t partBytes = (size_t)N * D * 4;            // 16.8 MB each
  const size_t partStride = (size_t)N * D;               // floats
  const size_t avail = (ws_size > base) ? (ws_size - base) : 0;

  int S = 0;
  if (avail >= pBytes) {
    const size_t extra = avail - pBytes;
    S = (extra >= 4 * partBytes) ? 4 : (extra >= 2 * partBytes) ? 2 : 1;
  }
  float* parts = (float*)(ws + base + pBytes);

  // --- prep ---
  hipMemsetAsync(l, 0, (size_t)N * 4, stream);
  transpose_h_kernel<<<dim3(D / 64, N / 64), 256, 0, stream>>>(H, HbT8, Hb, N, D);
  transpose_w_kernel<<<dim3(D / 64, D / 64), 256, 0, stream>>>(Wq, BqkT, D, D);
  transpose_w_kernel<<<dim3(D / 64, D / 64), 256, 0, stream>>>(Wk, BqkT + (size_t)D * D, D, D);
  pack_bias_kernel<<<dim3(4), 256, 0, stream>>>(bq, bk, bqk);

  // --- merged Q|K projection -> fp8: QK8[8192][1024] ---
  gemm_proj<<<dim3(2 * D / 128, N / 128), 256, 0, stream>>>(
      Hb, BqkT, 2 * D, D, bqk, QK8);

  if (S >= 1) {
    // scores: P8 = fp8(exp(diag0(Q K^T)*scale)), fused row-sums into l
    gemm_qk8<<<dim3(N / 128, N / 128), 256, 0, stream>>>(
        QK8, QK8 + D, N, D, 2 * D, 2 * D, l, 0, P8);
    if (S == 1) {
      gemm_pv8<true><<<dim3(D / 128, N / 64, 1), 256, 0, stream>>>(
          P8, HbT8, N, l, H, 0, out, 0);
    } else {
      gemm_pv8<false><<<dim3(D / 128, N / 64, S), 256, 0, stream>>>(
          P8, HbT8, N / S, nullptr, nullptr, 0, parts, partStride);
      combine_kernel<<<dim3((N * D / 4 + 255) / 256), 256, 0, stream>>>(
          parts, partStride, S, l, H, out, N * D / 4);
    }
  } else {
    // ws too small for full P8: chunk rows (direct PV per chunk)
    int maxRows = (int)(avail / (size_t)N);
    maxRows &= ~127;
    if (maxRows < 128) maxRows = 128;
    for (int r0 = 0; r0 < N; r0 += maxRows) {
      int rows = N - r0;
      if (rows > maxRows) rows = maxRows;
      gemm_qk8<<<dim3(N / 128, rows / 128), 256, 0, stream>>>(
          QK8 + (size_t)r0 * 2 * D, QK8 + D, N, D, 2 * D, 2 * D, l, r0, P8);
      gemm_pv8<true><<<dim3(D / 128, rows / 64, 1), 256, 0, stream>>>(
          P8, HbT8, N, l, H, r0, out, 0);
    }
  }
}

// Round 7
// 281.307 us; speedup vs baseline: 1.0779x; 1.0779x over previous
//
#include <hip/hip_runtime.h>
#include <cstdint>
#include <cstddef>

#define GLOBAL_AS __attribute__((address_space(1)))
#define LDS_AS __attribute__((address_space(3)))

typedef __attribute__((ext_vector_type(8))) short short8;
typedef __attribute__((ext_vector_type(4))) float floatx4;
typedef __attribute__((ext_vector_type(2))) long long2v;   // 16B LDS read

#if defined(__has_builtin)
#if __has_builtin(__builtin_amdgcn_cvt_pk_fp8_f32)
#define HAVE_HW_FP8 1
#endif
#endif

static __device__ __forceinline__ unsigned short f2bf(float f) {
  uint32_t u = __builtin_bit_cast(uint32_t, f);
  u += 0x7fffu + ((u >> 16) & 1u);
  return (unsigned short)(u >> 16);
}

// OCP e4m3 encode (RNE, saturate to 448)
static __device__ __forceinline__ unsigned char f2fp8(float f) {
#ifdef HAVE_HW_FP8
  float c = fminf(fmaxf(f, -448.f), 448.f);
  return (unsigned char)(__builtin_amdgcn_cvt_pk_fp8_f32(c, 0.f, 0, false) & 0xff);
#else
  unsigned char s = 0;
  if (f < 0.f) { s = 0x80; f = -f; }
  if (f >= 448.f) return s | 0x7e;
  if (f < 0.015625f) { int r = (int)(f * 512.f + 0.5f); return s | (unsigned char)r; }
  uint32_t u = __builtin_bit_cast(uint32_t, f);
  int e = (int)((u >> 23) & 0xff) - 127;
  uint32_t keep = (u >> 20) & 7, rest = u & 0xfffffu;
  if (rest > 0x80000u || (rest == 0x80000u && (keep & 1))) ++keep;
  if (keep == 8) { keep = 0; ++e; }
  if (e > 8) return s | 0x7e;
  return s | (unsigned char)(((e + 7) << 3) | keep);
#endif
}

// pack 4 fp8 bytes (cols l15+{0,16,32,48}) into one dword, bytes in j order
static __device__ __forceinline__ uint32_t pack4fp8(const float e[4]) {
#ifdef HAVE_HW_FP8
  const uint32_t p01 = (uint32_t)__builtin_amdgcn_cvt_pk_fp8_f32(e[0], e[1], 0, false);
  const uint32_t p23 = (uint32_t)__builtin_amdgcn_cvt_pk_fp8_f32(e[2], e[3], 0, false);
  return (p01 & 0xffffu) | (p23 << 16);
#else
  return (uint32_t)f2fp8(e[0]) | ((uint32_t)f2fp8(e[1]) << 8) |
         ((uint32_t)f2fp8(e[2]) << 16) | ((uint32_t)f2fp8(e[3]) << 24);
#endif
}

// Transpose lane-local stride-16 byte layout into a coalesced dword:
// dest lane (quad,l15) gets cols 4*l15+{0..3}: byte (l15>>2) of w from lanes
// quad*16 + 4*(l15&3) + {0..3}.  4 shfls + pack.
static __device__ __forceinline__ uint32_t gather_dword(uint32_t w, int quad, int l15) {
  const int src = quad * 16 + 4 * (l15 & 3);
  const int sh = (l15 >> 2) * 8;
  const uint32_t v0 = (uint32_t)__shfl((int)w, src);
  const uint32_t v1 = (uint32_t)__shfl((int)w, src + 1);
  const uint32_t v2 = (uint32_t)__shfl((int)w, src + 2);
  const uint32_t v3 = (uint32_t)__shfl((int)w, src + 3);
  return ((v0 >> sh) & 0xffu) | (((v1 >> sh) & 0xffu) << 8) |
         (((v2 >> sh) & 0xffu) << 16) | (((v3 >> sh) & 0xffu) << 24);
}

static __device__ __forceinline__ void wait_vm0() {
  // vmcnt(0), expcnt/lgkmcnt unconstrained
  __builtin_amdgcn_s_waitcnt(0x0f70);
}

// ---------------------------------------------------------------------------
// Transpose H: fp32 [R][C] -> HbT8 fp8 [C][R], plus straight bf16 copy [R][C]
// ---------------------------------------------------------------------------
__global__ __launch_bounds__(256) void transpose_h_kernel(
    const float* __restrict__ in, unsigned char* __restrict__ outT8,
    unsigned short* __restrict__ outN, int R, int C) {
  __shared__ float t[64][65];
  const int bc = blockIdx.x * 64;
  const int br = blockIdx.y * 64;
  const int tc = threadIdx.x & 63;
  const int tr = threadIdx.x >> 6;
  for (int r = tr; r < 64; r += 4) {
    const float v = in[(size_t)(br + r) * C + bc + tc];
    t[r][tc] = v;
    outN[(size_t)(br + r) * C + bc + tc] = f2bf(v);
  }
  __syncthreads();
  for (int r = tr; r < 64; r += 4)
    outT8[(size_t)(bc + r) * R + br + tc] = f2fp8(t[tc][r]);
}

// Transpose weights: fp32 [R][C] -> bf16 [C][R]
__global__ __launch_bounds__(256) void transpose_w_kernel(
    const float* __restrict__ in, unsigned short* __restrict__ outT, int R, int C) {
  __shared__ float t[64][65];
  const int bc = blockIdx.x * 64;
  const int br = blockIdx.y * 64;
  const int tc = threadIdx.x & 63;
  const int tr = threadIdx.x >> 6;
  for (int r = tr; r < 64; r += 4)
    t[r][tc] = in[(size_t)(br + r) * C + bc + tc];
  __syncthreads();
  for (int r = tr; r < 64; r += 4)
    outT[(size_t)(bc + r) * R + br + tc] = f2bf(t[tc][r]);
}

__global__ __launch_bounds__(256) void pack_bias_kernel(
    const float* __restrict__ bq, const float* __restrict__ bk,
    float* __restrict__ bqk) {
  int i = blockIdx.x * 256 + threadIdx.x;
  bqk[i] = (i < 512) ? bq[i] : bk[i - 512];
}

// ---------------------------------------------------------------------------
// Projection GEMM (bf16 x bf16 -> fp8): QK8[m][n] = fp8(A[m][k]*Bt[n][k]+b[n])
// 128x128 tile, BK=32, double-buffered one-barrier K-loop.
// Coalesced fp8 stores via gather_dword.
// ---------------------------------------------------------------------------
__global__ __launch_bounds__(256, 4) void gemm_proj(
    const unsigned short* __restrict__ A,    // Hb [8192][512] bf16
    const unsigned short* __restrict__ Bt,   // BqkT [1024][512] bf16
    int Ncols, int K,
    const float* __restrict__ bias,
    unsigned char* __restrict__ C8)          // QK8 [8192][1024] fp8
{
  __shared__ unsigned short As[2][128 * 32];
  __shared__ unsigned short Bs[2][128 * 32];

  const int tid  = threadIdx.x;
  const int lane = tid & 63;
  const int wave = tid >> 6;
  const int wr   = (wave >> 1) * 64;
  const int wc   = (wave & 1) * 64;
  const int quad = lane >> 4;
  const int l15  = lane & 15;
  const int bm   = blockIdx.y * 128;
  const int bn   = blockIdx.x * 128;

  const int c0 = tid, c1 = tid + 256;
  const int r0a = c0 >> 2, k0a = (c0 & 3) << 3;
  const int r1a = c1 >> 2, k1a = (c1 & 3) << 3;

  auto stage = [&](int kt, int b) {
    __builtin_amdgcn_global_load_lds(
        (const GLOBAL_AS void*)(A + (size_t)(bm + r0a) * K + kt + k0a),
        (LDS_AS void*)(&As[b][c0 * 8]), 16, 0, 0);
    __builtin_amdgcn_global_load_lds(
        (const GLOBAL_AS void*)(A + (size_t)(bm + r1a) * K + kt + k1a),
        (LDS_AS void*)(&As[b][c1 * 8]), 16, 0, 0);
    __builtin_amdgcn_global_load_lds(
        (const GLOBAL_AS void*)(Bt + (size_t)(bn + r0a) * K + kt + k0a),
        (LDS_AS void*)(&Bs[b][c0 * 8]), 16, 0, 0);
    __builtin_amdgcn_global_load_lds(
        (const GLOBAL_AS void*)(Bt + (size_t)(bn + r1a) * K + kt + k1a),
        (LDS_AS void*)(&Bs[b][c1 * 8]), 16, 0, 0);
  };

  floatx4 acc[4][4];
#pragma unroll
  for (int i = 0; i < 4; ++i)
#pragma unroll
    for (int j = 0; j < 4; ++j)
      acc[i][j] = (floatx4){0.f, 0.f, 0.f, 0.f};

  stage(0, 0);
  const int nIter = K >> 5;
  for (int it = 0; it < nIter; ++it) {
    const int b = it & 1;
    wait_vm0();
    __syncthreads();
    if (it + 1 < nIter) stage((it + 1) << 5, b ^ 1);

    short8 af[4], bfr[4];
#pragma unroll
    for (int i = 0; i < 4; ++i)
      af[i] = *(const short8*)(&As[b][(wr + i * 16 + l15) * 32 + quad * 8]);
#pragma unroll
    for (int j = 0; j < 4; ++j)
      bfr[j] = *(const short8*)(&Bs[b][(wc + j * 16 + l15) * 32 + quad * 8]);
#pragma unroll
    for (int i = 0; i < 4; ++i)
#pragma unroll
      for (int j = 0; j < 4; ++j)
        acc[i][j] = __builtin_amdgcn_mfma_f32_16x16x32_bf16(af[i], bfr[j], acc[i][j], 0, 0, 0);
  }

  // epilogue — C/D layout: col = lane&15, row = quad*4 + reg
#pragma unroll
  for (int i = 0; i < 4; ++i) {
    const int rl = bm + wr + i * 16 + quad * 4;
#pragma unroll
    for (int r = 0; r < 4; ++r) {
      const int row = rl + r;
      float e[4];
#pragma unroll
      for (int j = 0; j < 4; ++j)
        e[j] = acc[i][j][r] + bias[bn + wc + j * 16 + l15];
      const uint32_t d = gather_dword(pack4fp8(e), quad, l15);
      *(uint32_t*)(C8 + (size_t)row * Ncols + bn + wc + 4 * l15) = d;
    }
  }
}

// ---------------------------------------------------------------------------
// Scores GEMM fp8 x fp8: P8 = fp8(exp(diag0(Q K^T)*scale)), fused row-sums.
// 128x128 tile, BK=64, double-buffered one-barrier loop.
// K-permutation trick: mfma call t, quad q covers global k = q*16 + t*8 + j ->
// each lane's fragment is one contiguous 16B ds_read_b128 at row*64 + quad*16.
// (256,4): register ceiling — ~56 VGPR + 64 AGPR acc = ~120 unified regs/wave
// caps HW at 4 waves/SIMD; do NOT raise (r6: (256,5) squeezed VGPR, -20%).
// ---------------------------------------------------------------------------
__global__ __launch_bounds__(256, 4) void gemm_qk8(
    const unsigned char* __restrict__ A,     // Q8 rows [.][lda] fp8
    const unsigned char* __restrict__ Bt,    // K8 [8192][ldb] fp8
    int Ncols, int K, int lda, int ldb,
    float* __restrict__ lsum,
    int row0,
    unsigned char* __restrict__ P8)
{
  __shared__ unsigned char As[2][128 * 64];   // 8 KiB x2
  __shared__ unsigned char Bs[2][128 * 64];   // 8 KiB x2

  const int tid  = threadIdx.x;
  const int lane = tid & 63;
  const int wave = tid >> 6;
  const int wr   = (wave >> 1) * 64;
  const int wc   = (wave & 1) * 64;
  const int quad = lane >> 4;
  const int l15  = lane & 15;
  const int bm   = blockIdx.y * 128;
  const int bn   = blockIdx.x * 128;

  // staging: 512 chunks of 16B cover 128 rows x 64B; c -> row c>>2, kofs (c&3)*16
  const int c0 = tid, c1 = tid + 256;
  const int r0a = c0 >> 2, k0a = (c0 & 3) << 4;
  const int r1a = c1 >> 2, k1a = (c1 & 3) << 4;

  auto stage = [&](int kt, int b) {
    __builtin_amdgcn_global_load_lds(
        (const GLOBAL_AS void*)(A + (size_t)(bm + r0a) * lda + kt + k0a),
        (LDS_AS void*)(&As[b][c0 * 16]), 16, 0, 0);
    __builtin_amdgcn_global_load_lds(
        (const GLOBAL_AS void*)(A + (size_t)(bm + r1a) * lda + kt + k1a),
        (LDS_AS void*)(&As[b][c1 * 16]), 16, 0, 0);
    __builtin_amdgcn_global_load_lds(
        (const GLOBAL_AS void*)(Bt + (size_t)(bn + r0a) * ldb + kt + k0a),
        (LDS_AS void*)(&Bs[b][c0 * 16]), 16, 0, 0);
    __builtin_amdgcn_global_load_lds(
        (const GLOBAL_AS void*)(Bt + (size_t)(bn + r1a) * ldb + kt + k1a),
        (LDS_AS void*)(&Bs[b][c1 * 16]), 16, 0, 0);
  };

  floatx4 acc[4][4];
#pragma unroll
  for (int i = 0; i < 4; ++i)
#pragma unroll
    for (int j = 0; j < 4; ++j)
      acc[i][j] = (floatx4){0.f, 0.f, 0.f, 0.f};

  stage(0, 0);
  const int nIter = K >> 6;
  for (int it = 0; it < nIter; ++it) {
    const int b = it & 1;
    wait_vm0();
    __syncthreads();
    if (it + 1 < nIter) stage((it + 1) << 6, b ^ 1);

    long2v af[4], bfr[4];
#pragma unroll
    for (int i = 0; i < 4; ++i)
      af[i] = *(const long2v*)(&As[b][(wr + i * 16 + l15) * 64 + quad * 16]);
#pragma unroll
    for (int j = 0; j < 4; ++j)
      bfr[j] = *(const long2v*)(&Bs[b][(wc + j * 16 + l15) * 64 + quad * 16]);
#pragma unroll
    for (int i = 0; i < 4; ++i)
#pragma unroll
      for (int j = 0; j < 4; ++j) {
        acc[i][j] = __builtin_amdgcn_mfma_f32_16x16x32_fp8_fp8(af[i].x, bfr[j].x, acc[i][j], 0, 0, 0);
        acc[i][j] = __builtin_amdgcn_mfma_f32_16x16x32_fp8_fp8(af[i].y, bfr[j].y, acc[i][j], 0, 0, 0);
      }
  }

  const float scale = 0.044194173824159216f;  // 1/sqrt(512)
#pragma unroll
  for (int i = 0; i < 4; ++i) {
    const int rl = bm + wr + i * 16 + quad * 4;
#pragma unroll
    for (int r = 0; r < 4; ++r) {
      const int row = rl + r;
      float e[4];
#pragma unroll
      for (int j = 0; j < 4; ++j) {
        const int col = bn + wc + j * 16 + l15;
        const float lg = ((row0 + row) == col) ? 0.f : acc[i][j][r] * scale;
        e[j] = fminf(__expf(lg), 448.f);
      }
      // row-sum from fp32 values (fp8 num/denom inconsistency ~0.004% on l)
      float rsum = (e[0] + e[1]) + (e[2] + e[3]);
      const uint32_t d = gather_dword(pack4fp8(e), quad, l15);
      *(uint32_t*)(P8 + (size_t)row * Ncols + bn + wc + 4 * l15) = d;
      rsum += __shfl_xor(rsum, 1);
      rsum += __shfl_xor(rsum, 2);
      rsum += __shfl_xor(rsum, 4);
      rsum += __shfl_xor(rsum, 8);
      if (l15 == 0) atomicAdd(&lsum[row0 + row], rsum);
    }
  }
}

// ---------------------------------------------------------------------------
// PV GEMM fp8 x fp8: O[m][n] = sum_k P8[m][k]*HbT8[n][k]. 64x128 tile, BK=64,
// double-buffered, split-K over z. Same K-permutation b128 trick as gemm_qk8.
// (256,6): regs 40+32acc=72 -> HW caps ~7 waves/SIMD; LDS 24KB x6 = 144KB.
// ---------------------------------------------------------------------------
template <bool DIRECT>
__global__ __launch_bounds__(256, 6) void gemm_pv8(
    const unsigned char* __restrict__ P,     // [rows][8192] fp8 (chunk base)
    const unsigned char* __restrict__ Bt,    // HbT8 [512][8192] fp8
    int Kchunk,
    const float* __restrict__ lvec,
    const float* __restrict__ Hres,
    int row0,
    float* __restrict__ outp,
    size_t partStride)
{
  __shared__ unsigned char As[2][64 * 64];    // 4 KiB x2
  __shared__ unsigned char Bs[2][128 * 64];   // 8 KiB x2

  const int tid  = threadIdx.x;
  const int lane = tid & 63;
  const int wave = tid >> 6;
  const int wr   = (wave >> 1) * 32;
  const int wc   = (wave & 1) * 64;
  const int quad = lane >> 4;
  const int l15  = lane & 15;
  const int bm   = blockIdx.y * 64;
  const int bn   = blockIdx.x * 128;
  const int k0   = blockIdx.z * Kchunk;

  float* part = outp + (DIRECT ? 0 : (size_t)blockIdx.z * partStride);

  const int rA = tid >> 2,  kA = (tid & 3) << 4;    // 256 chunks: 64 rows x 64B
  const int cB1 = tid + 256;
  const int rB0 = tid >> 2, kB0 = (tid & 3) << 4;   // 512 chunks: 128 rows x 64B
  const int rB1 = cB1 >> 2, kB1 = (cB1 & 3) << 4;

  auto stage = [&](int kt, int b) {
    __builtin_amdgcn_global_load_lds(
        (const GLOBAL_AS void*)(P + (size_t)(bm + rA) * 8192 + kt + kA),
        (LDS_AS void*)(&As[b][tid * 16]), 16, 0, 0);
    __builtin_amdgcn_global_load_lds(
        (const GLOBAL_AS void*)(Bt + (size_t)(bn + rB0) * 8192 + kt + kB0),
        (LDS_AS void*)(&Bs[b][tid * 16]), 16, 0, 0);
    __builtin_amdgcn_global_load_lds(
        (const GLOBAL_AS void*)(Bt + (size_t)(bn + rB1) * 8192 + kt + kB1),
        (LDS_AS void*)(&Bs[b][cB1 * 16]), 16, 0, 0);
  };

  floatx4 acc[2][4];
#pragma unroll
  for (int i = 0; i < 2; ++i)
#pragma unroll
    for (int j = 0; j < 4; ++j)
      acc[i][j] = (floatx4){0.f, 0.f, 0.f, 0.f};

  stage(k0, 0);
  const int nIter = Kchunk >> 6;
  for (int it = 0; it < nIter; ++it) {
    const int b = it & 1;
    wait_vm0();
    __syncthreads();
    if (it + 1 < nIter) stage(k0 + ((it + 1) << 6), b ^ 1);

    long2v af[2], bfr[4];
#pragma unroll
    for (int i = 0; i < 2; ++i)
      af[i] = *(const long2v*)(&As[b][(wr + i * 16 + l15) * 64 + quad * 16]);
#pragma unroll
    for (int j = 0; j < 4; ++j)
      bfr[j] = *(const long2v*)(&Bs[b][(wc + j * 16 + l15) * 64 + quad * 16]);
#pragma unroll
    for (int i = 0; i < 2; ++i)
#pragma unroll
      for (int j = 0; j < 4; ++j) {
        acc[i][j] = __builtin_amdgcn_mfma_f32_16x16x32_fp8_fp8(af[i].x, bfr[j].x, acc[i][j], 0, 0, 0);
        acc[i][j] = __builtin_amdgcn_mfma_f32_16x16x32_fp8_fp8(af[i].y, bfr[j].y, acc[i][j], 0, 0, 0);
      }
  }

#pragma unroll
  for (int i = 0; i < 2; ++i) {
    const int rl = bm + wr + i * 16 + quad * 4;
#pragma unroll
    for (int j = 0; j < 4; ++j) {
      const int col = bn + wc + j * 16 + l15;
#pragma unroll
      for (int r = 0; r < 4; ++r) {
        const int row = rl + r;
        const float v = acc[i][j][r];
        if (DIRECT) {
          const int grow = row0 + row;
          part[(size_t)grow * 512 + col] =
              v / lvec[grow] + Hres[(size_t)grow * 512 + col];
        } else {
          part[(size_t)row * 512 + col] = v;
        }
      }
    }
  }
}

// combine: out = (sum_s partial_s) / l[row] + H
__global__ __launch_bounds__(256) void combine_kernel(
    const float* __restrict__ parts, size_t partStride, int S,
    const float* __restrict__ lvec, const float* __restrict__ Hres,
    float* __restrict__ out, int n4) {
  int i = blockIdx.x * 256 + threadIdx.x;
  if (i >= n4) return;
  float4 a = ((const float4*)parts)[i];
  for (int s = 1; s < S; ++s) {
    const float4 b = ((const float4*)(parts + (size_t)s * partStride))[i];
    a.x += b.x; a.y += b.y; a.z += b.z; a.w += b.w;
  }
  const int row = i >> 7;
  const float inv = 1.f / lvec[row];
  const float4 h = ((const float4*)Hres)[i];
  float4 o;
  o.x = a.x * inv + h.x;
  o.y = a.y * inv + h.y;
  o.z = a.z * inv + h.z;
  o.w = a.w * inv + h.w;
  ((float4*)out)[i] = o;
}

// ---------------------------------------------------------------------------
extern "C" void kernel_launch(void* const* d_in, const int* in_sizes, int n_in,
                              void* d_out, int out_size, void* d_ws, size_t ws_size,
                              hipStream_t stream) {
  const float* H  = (const float*)d_in[0];
  const float* Wq = (const float*)d_in[1];
  const float* bq = (const float*)d_in[2];
  const float* Wk = (const float*)d_in[3];
  const float* bk = (const float*)d_in[4];
  float* out = (float*)d_out;

  const int N = 8192, D = 512;

  char* ws = (char*)d_ws;
  size_t off = 0;
  auto alloc = [&](size_t bytes) { char* p = ws + off; off += bytes; return p; };
  unsigned short* Hb   = (unsigned short*)alloc((size_t)N * D * 2);       // 8 MB
  unsigned char*  HbT8 = (unsigned char*)alloc((size_t)D * N);            // 4.2 MB
  unsigned char*  QK8  = (unsigned char*)alloc((size_t)N * 2 * D);        // 8.4 MB
  unsigned short* BqkT = (unsigned short*)alloc((size_t)2 * D * D * 2);   // 1 MB
  float* bqk = (float*)alloc((size_t)2 * D * 4);
  float* l   = (float*)alloc((size_t)N * 4);
  const size_t base = off;
  unsigned char* P8 = (unsigned char*)(ws + base);

  const size_t pBytes = (size_t)N * N;                   // 67 MB (fp8)
  const size_t partBytes = (size_t)N * D * 4;            // 16.8 MB each
  const size_t partStride = (size_t)N * D;               // floats
  const size_t avail = (ws_size > base) ? (ws_size - base) : 0;

  int S = 0;
  if (avail >= pBytes) {
    const size_t extra = avail - pBytes;
    S = (extra >= 4 * partBytes) ? 4 : (extra >= 2 * partBytes) ? 2 : 1;
  }
  float* parts = (float*)(ws + base + pBytes);

  // --- prep ---
  hipMemsetAsync(l, 0, (size_t)N * 4, stream);
  transpose_h_kernel<<<dim3(D / 64, N / 64), 256, 0, stream>>>(H, HbT8, Hb, N, D);
  transpose_w_kernel<<<dim3(D / 64, D / 64), 256, 0, stream>>>(Wq, BqkT, D, D);
  transpose_w_kernel<<<dim3(D / 64, D / 64), 256, 0, stream>>>(Wk, BqkT + (size_t)D * D, D, D);
  pack_bias_kernel<<<dim3(4), 256, 0, stream>>>(bq, bk, bqk);

  // --- merged Q|K projection -> fp8: QK8[8192][1024] ---
  gemm_proj<<<dim3(2 * D / 128, N / 128), 256, 0, stream>>>(
      Hb, BqkT, 2 * D, D, bqk, QK8);

  if (S >= 1) {
    // scores: P8 = fp8(exp(diag0(Q K^T)*scale)), fused row-sums into l
    gemm_qk8<<<dim3(N / 128, N / 128), 256, 0, stream>>>(
        QK8, QK8 + D, N, D, 2 * D, 2 * D, l, 0, P8);
    if (S == 1) {
      gemm_pv8<true><<<dim3(D / 128, N / 64, 1), 256, 0, stream>>>(
          P8, HbT8, N, l, H, 0, out, 0);
    } else {
      gemm_pv8<false><<<dim3(D / 128, N / 64, S), 256, 0, stream>>>(
          P8, HbT8, N / S, nullptr, nullptr, 0, parts, partStride);
      combine_kernel<<<dim3((N * D / 4 + 255) / 256), 256, 0, stream>>>(
          parts, partStride, S, l, H, out, N * D / 4);
    }
  } else {
    // ws too small for full P8: chunk rows (direct PV per chunk)
    int maxRows = (int)(avail / (size_t)N);
    maxRows &= ~127;
    if (maxRows < 128) maxRows = 128;
    for (int r0 = 0; r0 < N; r0 += maxRows) {
      int rows = N - r0;
      if (rows > maxRows) rows = maxRows;
      gemm_qk8<<<dim3(N / 128, rows / 128), 256, 0, stream>>>(
          QK8 + (size_t)r0 * 2 * D, QK8 + D, N, D, 2 * D, 2 * D, l, r0, P8);
      gemm_pv8<true><<<dim3(D / 128, rows / 64, 1), 256, 0, stream>>>(
          P8, HbT8, N, l, H, r0, out, 0);
    }
  }
}

// Round 8
// 269.698 us; speedup vs baseline: 1.1243x; 1.0430x over previous
//
#include <hip/hip_runtime.h>
#include <cstdint>
#include <cstddef>

#define GLOBAL_AS __attribute__((address_space(1)))
#define LDS_AS __attribute__((address_space(3)))

typedef __attribute__((ext_vector_type(8))) short short8;
typedef __attribute__((ext_vector_type(4))) float floatx4;
typedef __attribute__((ext_vector_type(2))) long long2v;   // 16B LDS read

#if defined(__has_builtin)
#if __has_builtin(__builtin_amdgcn_cvt_pk_fp8_f32)
#define HAVE_HW_FP8 1
#endif
#endif

static __device__ __forceinline__ unsigned short f2bf(float f) {
  uint32_t u = __builtin_bit_cast(uint32_t, f);
  u += 0x7fffu + ((u >> 16) & 1u);
  return (unsigned short)(u >> 16);
}

// OCP e4m3 encode (RNE, saturate to 448)
static __device__ __forceinline__ unsigned char f2fp8(float f) {
#ifdef HAVE_HW_FP8
  float c = fminf(fmaxf(f, -448.f), 448.f);
  return (unsigned char)(__builtin_amdgcn_cvt_pk_fp8_f32(c, 0.f, 0, false) & 0xff);
#else
  unsigned char s = 0;
  if (f < 0.f) { s = 0x80; f = -f; }
  if (f >= 448.f) return s | 0x7e;
  if (f < 0.015625f) { int r = (int)(f * 512.f + 0.5f); return s | (unsigned char)r; }
  uint32_t u = __builtin_bit_cast(uint32_t, f);
  int e = (int)((u >> 23) & 0xff) - 127;
  uint32_t keep = (u >> 20) & 7, rest = u & 0xfffffu;
  if (rest > 0x80000u || (rest == 0x80000u && (keep & 1))) ++keep;
  if (keep == 8) { keep = 0; ++e; }
  if (e > 8) return s | 0x7e;
  return s | (unsigned char)(((e + 7) << 3) | keep);
#endif
}

// pack 4 fp8 bytes (cols l15+{0,16,32,48}) into one dword, bytes in j order
static __device__ __forceinline__ uint32_t pack4fp8(const float e[4]) {
#ifdef HAVE_HW_FP8
  const uint32_t p01 = (uint32_t)__builtin_amdgcn_cvt_pk_fp8_f32(e[0], e[1], 0, false);
  const uint32_t p23 = (uint32_t)__builtin_amdgcn_cvt_pk_fp8_f32(e[2], e[3], 0, false);
  return (p01 & 0xffffu) | (p23 << 16);
#else
  return (uint32_t)f2fp8(e[0]) | ((uint32_t)f2fp8(e[1]) << 8) |
         ((uint32_t)f2fp8(e[2]) << 16) | ((uint32_t)f2fp8(e[3]) << 24);
#endif
}

// Transpose lane-local stride-16 byte layout into a coalesced dword:
// dest lane (quad,l15) gets cols 4*l15+{0..3}: byte (l15>>2) of w from lanes
// quad*16 + 4*(l15&3) + {0..3}.  4 shfls + pack.
static __device__ __forceinline__ uint32_t gather_dword(uint32_t w, int quad, int l15) {
  const int src = quad * 16 + 4 * (l15 & 3);
  const int sh = (l15 >> 2) * 8;
  const uint32_t v0 = (uint32_t)__shfl((int)w, src);
  const uint32_t v1 = (uint32_t)__shfl((int)w, src + 1);
  const uint32_t v2 = (uint32_t)__shfl((int)w, src + 2);
  const uint32_t v3 = (uint32_t)__shfl((int)w, src + 3);
  return ((v0 >> sh) & 0xffu) | (((v1 >> sh) & 0xffu) << 8) |
         (((v2 >> sh) & 0xffu) << 16) | (((v3 >> sh) & 0xffu) << 24);
}

static __device__ __forceinline__ void wait_vm0() {
  // vmcnt(0), expcnt/lgkmcnt unconstrained
  __builtin_amdgcn_s_waitcnt(0x0f70);
}

// ---------------------------------------------------------------------------
// Transpose H: fp32 [R][C] -> HbT8 fp8 [C][R], plus straight bf16 copy [R][C]
// ---------------------------------------------------------------------------
__global__ __launch_bounds__(256) void transpose_h_kernel(
    const float* __restrict__ in, unsigned char* __restrict__ outT8,
    unsigned short* __restrict__ outN, int R, int C) {
  __shared__ float t[64][65];
  const int bc = blockIdx.x * 64;
  const int br = blockIdx.y * 64;
  const int tc = threadIdx.x & 63;
  const int tr = threadIdx.x >> 6;
  for (int r = tr; r < 64; r += 4) {
    const float v = in[(size_t)(br + r) * C + bc + tc];
    t[r][tc] = v;
    outN[(size_t)(br + r) * C + bc + tc] = f2bf(v);
  }
  __syncthreads();
  for (int r = tr; r < 64; r += 4)
    outT8[(size_t)(bc + r) * R + br + tc] = f2fp8(t[tc][r]);
}

// Transpose weights: fp32 [R][C] -> bf16 [C][R]
__global__ __launch_bounds__(256) void transpose_w_kernel(
    const float* __restrict__ in, unsigned short* __restrict__ outT, int R, int C) {
  __shared__ float t[64][65];
  const int bc = blockIdx.x * 64;
  const int br = blockIdx.y * 64;
  const int tc = threadIdx.x & 63;
  const int tr = threadIdx.x >> 6;
  for (int r = tr; r < 64; r += 4)
    t[r][tc] = in[(size_t)(br + r) * C + bc + tc];
  __syncthreads();
  for (int r = tr; r < 64; r += 4)
    outT[(size_t)(bc + r) * R + br + tc] = f2bf(t[tc][r]);
}

__global__ __launch_bounds__(256) void pack_bias_kernel(
    const float* __restrict__ bq, const float* __restrict__ bk,
    float* __restrict__ bqk) {
  int i = blockIdx.x * 256 + threadIdx.x;
  bqk[i] = (i < 512) ? bq[i] : bk[i - 512];
}

// ---------------------------------------------------------------------------
// Projection GEMM (bf16 x bf16 -> fp8): QK8[m][n] = fp8(A[m][k]*Bt[n][k]+b[n])
// 128x128 tile, BK=32, double-buffered one-barrier K-loop.
// Coalesced fp8 stores via gather_dword.
// ---------------------------------------------------------------------------
__global__ __launch_bounds__(256, 4) void gemm_proj(
    const unsigned short* __restrict__ A,    // Hb [8192][512] bf16
    const unsigned short* __restrict__ Bt,   // BqkT [1024][512] bf16
    int Ncols, int K,
    const float* __restrict__ bias,
    unsigned char* __restrict__ C8)          // QK8 [8192][1024] fp8
{
  __shared__ unsigned short As[2][128 * 32];
  __shared__ unsigned short Bs[2][128 * 32];

  const int tid  = threadIdx.x;
  const int lane = tid & 63;
  const int wave = tid >> 6;
  const int wr   = (wave >> 1) * 64;
  const int wc   = (wave & 1) * 64;
  const int quad = lane >> 4;
  const int l15  = lane & 15;
  const int bm   = blockIdx.y * 128;
  const int bn   = blockIdx.x * 128;

  const int c0 = tid, c1 = tid + 256;
  const int r0a = c0 >> 2, k0a = (c0 & 3) << 3;
  const int r1a = c1 >> 2, k1a = (c1 & 3) << 3;

  auto stage = [&](int kt, int b) {
    __builtin_amdgcn_global_load_lds(
        (const GLOBAL_AS void*)(A + (size_t)(bm + r0a) * K + kt + k0a),
        (LDS_AS void*)(&As[b][c0 * 8]), 16, 0, 0);
    __builtin_amdgcn_global_load_lds(
        (const GLOBAL_AS void*)(A + (size_t)(bm + r1a) * K + kt + k1a),
        (LDS_AS void*)(&As[b][c1 * 8]), 16, 0, 0);
    __builtin_amdgcn_global_load_lds(
        (const GLOBAL_AS void*)(Bt + (size_t)(bn + r0a) * K + kt + k0a),
        (LDS_AS void*)(&Bs[b][c0 * 8]), 16, 0, 0);
    __builtin_amdgcn_global_load_lds(
        (const GLOBAL_AS void*)(Bt + (size_t)(bn + r1a) * K + kt + k1a),
        (LDS_AS void*)(&Bs[b][c1 * 8]), 16, 0, 0);
  };

  floatx4 acc[4][4];
#pragma unroll
  for (int i = 0; i < 4; ++i)
#pragma unroll
    for (int j = 0; j < 4; ++j)
      acc[i][j] = (floatx4){0.f, 0.f, 0.f, 0.f};

  stage(0, 0);
  const int nIter = K >> 5;
  for (int it = 0; it < nIter; ++it) {
    const int b = it & 1;
    wait_vm0();
    __syncthreads();
    if (it + 1 < nIter) stage((it + 1) << 5, b ^ 1);

    short8 af[4], bfr[4];
#pragma unroll
    for (int i = 0; i < 4; ++i)
      af[i] = *(const short8*)(&As[b][(wr + i * 16 + l15) * 32 + quad * 8]);
#pragma unroll
    for (int j = 0; j < 4; ++j)
      bfr[j] = *(const short8*)(&Bs[b][(wc + j * 16 + l15) * 32 + quad * 8]);
#pragma unroll
    for (int i = 0; i < 4; ++i)
#pragma unroll
      for (int j = 0; j < 4; ++j)
        acc[i][j] = __builtin_amdgcn_mfma_f32_16x16x32_bf16(af[i], bfr[j], acc[i][j], 0, 0, 0);
  }

  // epilogue — C/D layout: col = lane&15, row = quad*4 + reg
#pragma unroll
  for (int i = 0; i < 4; ++i) {
    const int rl = bm + wr + i * 16 + quad * 4;
#pragma unroll
    for (int r = 0; r < 4; ++r) {
      const int row = rl + r;
      float e[4];
#pragma unroll
      for (int j = 0; j < 4; ++j)
        e[j] = acc[i][j][r] + bias[bn + wc + j * 16 + l15];
      const uint32_t d = gather_dword(pack4fp8(e), quad, l15);
      *(uint32_t*)(C8 + (size_t)row * Ncols + bn + wc + 4 * l15) = d;
    }
  }
}

// ---------------------------------------------------------------------------
// Scores GEMM fp8 x fp8: P8 = fp8(exp(diag0(Q K^T)*scale)), fused row-sums.
// 128x128 tile, BK=64, double-buffered one-barrier loop.
// 512 THREADS / 8 waves in a 4x2 grid (wave-tile 32x64): acc[2][4] = 32 AGPR
// cuts per-wave regs ~120 -> ~82, lifting the register occupancy ceiling
// from 4 to 6 waves/SIMD (r6/r7 showed 4-wave cap was the stall source).
// __launch_bounds__(512,6): 85-reg budget, 3 blocks/CU (96 KB LDS).
// K-permutation trick unchanged: lane fragment = one contiguous 16B
// ds_read_b128 at row*64 + quad*16.
// ---------------------------------------------------------------------------
__global__ __launch_bounds__(512, 6) void gemm_qk8(
    const unsigned char* __restrict__ A,     // Q8 rows [.][lda] fp8
    const unsigned char* __restrict__ Bt,    // K8 [8192][ldb] fp8
    int Ncols, int K, int lda, int ldb,
    float* __restrict__ lsum,
    int row0,
    unsigned char* __restrict__ P8)
{
  __shared__ unsigned char As[2][128 * 64];   // 8 KiB x2
  __shared__ unsigned char Bs[2][128 * 64];   // 8 KiB x2

  const int tid  = threadIdx.x;
  const int lane = tid & 63;
  const int wave = tid >> 6;           // 0..7
  const int wr   = (wave >> 1) * 32;   // 0,32,64,96
  const int wc   = (wave & 1) * 64;    // 0,64
  const int quad = lane >> 4;
  const int l15  = lane & 15;
  const int bm   = blockIdx.y * 128;
  const int bn   = blockIdx.x * 128;

  // staging: 512 chunks of 16B cover 128 rows x 64B; one A + one B per thread
  const int rS = tid >> 2, kS = (tid & 3) << 4;

  auto stage = [&](int kt, int b) {
    __builtin_amdgcn_global_load_lds(
        (const GLOBAL_AS void*)(A + (size_t)(bm + rS) * lda + kt + kS),
        (LDS_AS void*)(&As[b][tid * 16]), 16, 0, 0);
    __builtin_amdgcn_global_load_lds(
        (const GLOBAL_AS void*)(Bt + (size_t)(bn + rS) * ldb + kt + kS),
        (LDS_AS void*)(&Bs[b][tid * 16]), 16, 0, 0);
  };

  floatx4 acc[2][4];
#pragma unroll
  for (int i = 0; i < 2; ++i)
#pragma unroll
    for (int j = 0; j < 4; ++j)
      acc[i][j] = (floatx4){0.f, 0.f, 0.f, 0.f};

  stage(0, 0);
  const int nIter = K >> 6;
  for (int it = 0; it < nIter; ++it) {
    const int b = it & 1;
    wait_vm0();
    __syncthreads();
    if (it + 1 < nIter) stage((it + 1) << 6, b ^ 1);

    long2v af[2], bfr[4];
#pragma unroll
    for (int i = 0; i < 2; ++i)
      af[i] = *(const long2v*)(&As[b][(wr + i * 16 + l15) * 64 + quad * 16]);
#pragma unroll
    for (int j = 0; j < 4; ++j)
      bfr[j] = *(const long2v*)(&Bs[b][(wc + j * 16 + l15) * 64 + quad * 16]);
#pragma unroll
    for (int i = 0; i < 2; ++i)
#pragma unroll
      for (int j = 0; j < 4; ++j) {
        acc[i][j] = __builtin_amdgcn_mfma_f32_16x16x32_fp8_fp8(af[i].x, bfr[j].x, acc[i][j], 0, 0, 0);
        acc[i][j] = __builtin_amdgcn_mfma_f32_16x16x32_fp8_fp8(af[i].y, bfr[j].y, acc[i][j], 0, 0, 0);
      }
  }

  const float scale = 0.044194173824159216f;  // 1/sqrt(512)
#pragma unroll
  for (int i = 0; i < 2; ++i) {
    const int rl = bm + wr + i * 16 + quad * 4;
#pragma unroll
    for (int r = 0; r < 4; ++r) {
      const int row = rl + r;
      float e[4];
#pragma unroll
      for (int j = 0; j < 4; ++j) {
        const int col = bn + wc + j * 16 + l15;
        const float lg = ((row0 + row) == col) ? 0.f : acc[i][j][r] * scale;
        e[j] = fminf(__expf(lg), 448.f);
      }
      // row-sum from fp32 values (fp8 num/denom inconsistency ~0.004% on l)
      float rsum = (e[0] + e[1]) + (e[2] + e[3]);
      const uint32_t d = gather_dword(pack4fp8(e), quad, l15);
      *(uint32_t*)(P8 + (size_t)row * Ncols + bn + wc + 4 * l15) = d;
      rsum += __shfl_xor(rsum, 1);
      rsum += __shfl_xor(rsum, 2);
      rsum += __shfl_xor(rsum, 4);
      rsum += __shfl_xor(rsum, 8);
      if (l15 == 0) atomicAdd(&lsum[row0 + row], rsum);
    }
  }
}

// ---------------------------------------------------------------------------
// PV GEMM fp8 x fp8: O[m][n] = sum_k P8[m][k]*HbT8[n][k]. 64x128 tile, BK=64,
// double-buffered, split-K over z. Same K-permutation b128 trick as gemm_qk8.
// (256,6): regs 40+32acc=72 -> HW caps ~7 waves/SIMD; LDS 24KB x6 = 144KB.
// ---------------------------------------------------------------------------
template <bool DIRECT>
__global__ __launch_bounds__(256, 6) void gemm_pv8(
    const unsigned char* __restrict__ P,     // [rows][8192] fp8 (chunk base)
    const unsigned char* __restrict__ Bt,    // HbT8 [512][8192] fp8
    int Kchunk,
    const float* __restrict__ lvec,
    const float* __restrict__ Hres,
    int row0,
    float* __restrict__ outp,
    size_t partStride)
{
  __shared__ unsigned char As[2][64 * 64];    // 4 KiB x2
  __shared__ unsigned char Bs[2][128 * 64];   // 8 KiB x2

  const int tid  = threadIdx.x;
  const int lane = tid & 63;
  const int wave = tid >> 6;
  const int wr   = (wave >> 1) * 32;
  const int wc   = (wave & 1) * 64;
  const int quad = lane >> 4;
  const int l15  = lane & 15;
  const int bm   = blockIdx.y * 64;
  const int bn   = blockIdx.x * 128;
  const int k0   = blockIdx.z * Kchunk;

  float* part = outp + (DIRECT ? 0 : (size_t)blockIdx.z * partStride);

  const int rA = tid >> 2,  kA = (tid & 3) << 4;    // 256 chunks: 64 rows x 64B
  const int cB1 = tid + 256;
  const int rB0 = tid >> 2, kB0 = (tid & 3) << 4;   // 512 chunks: 128 rows x 64B
  const int rB1 = cB1 >> 2, kB1 = (cB1 & 3) << 4;

  auto stage = [&](int kt, int b) {
    __builtin_amdgcn_global_load_lds(
        (const GLOBAL_AS void*)(P + (size_t)(bm + rA) * 8192 + kt + kA),
        (LDS_AS void*)(&As[b][tid * 16]), 16, 0, 0);
    __builtin_amdgcn_global_load_lds(
        (const GLOBAL_AS void*)(Bt + (size_t)(bn + rB0) * 8192 + kt + kB0),
        (LDS_AS void*)(&Bs[b][tid * 16]), 16, 0, 0);
    __builtin_amdgcn_global_load_lds(
        (const GLOBAL_AS void*)(Bt + (size_t)(bn + rB1) * 8192 + kt + kB1),
        (LDS_AS void*)(&Bs[b][cB1 * 16]), 16, 0, 0);
  };

  floatx4 acc[2][4];
#pragma unroll
  for (int i = 0; i < 2; ++i)
#pragma unroll
    for (int j = 0; j < 4; ++j)
      acc[i][j] = (floatx4){0.f, 0.f, 0.f, 0.f};

  stage(k0, 0);
  const int nIter = Kchunk >> 6;
  for (int it = 0; it < nIter; ++it) {
    const int b = it & 1;
    wait_vm0();
    __syncthreads();
    if (it + 1 < nIter) stage(k0 + ((it + 1) << 6), b ^ 1);

    long2v af[2], bfr[4];
#pragma unroll
    for (int i = 0; i < 2; ++i)
      af[i] = *(const long2v*)(&As[b][(wr + i * 16 + l15) * 64 + quad * 16]);
#pragma unroll
    for (int j = 0; j < 4; ++j)
      bfr[j] = *(const long2v*)(&Bs[b][(wc + j * 16 + l15) * 64 + quad * 16]);
#pragma unroll
    for (int i = 0; i < 2; ++i)
#pragma unroll
      for (int j = 0; j < 4; ++j) {
        acc[i][j] = __builtin_amdgcn_mfma_f32_16x16x32_fp8_fp8(af[i].x, bfr[j].x, acc[i][j], 0, 0, 0);
        acc[i][j] = __builtin_amdgcn_mfma_f32_16x16x32_fp8_fp8(af[i].y, bfr[j].y, acc[i][j], 0, 0, 0);
      }
  }

#pragma unroll
  for (int i = 0; i < 2; ++i) {
    const int rl = bm + wr + i * 16 + quad * 4;
#pragma unroll
    for (int j = 0; j < 4; ++j) {
      const int col = bn + wc + j * 16 + l15;
#pragma unroll
      for (int r = 0; r < 4; ++r) {
        const int row = rl + r;
        const float v = acc[i][j][r];
        if (DIRECT) {
          const int grow = row0 + row;
          part[(size_t)grow * 512 + col] =
              v / lvec[grow] + Hres[(size_t)grow * 512 + col];
        } else {
          part[(size_t)row * 512 + col] = v;
        }
      }
    }
  }
}

// combine: out = (sum_s partial_s) / l[row] + H
__global__ __launch_bounds__(256) void combine_kernel(
    const float* __restrict__ parts, size_t partStride, int S,
    const float* __restrict__ lvec, const float* __restrict__ Hres,
    float* __restrict__ out, int n4) {
  int i = blockIdx.x * 256 + threadIdx.x;
  if (i >= n4) return;
  float4 a = ((const float4*)parts)[i];
  for (int s = 1; s < S; ++s) {
    const float4 b = ((const float4*)(parts + (size_t)s * partStride))[i];
    a.x += b.x; a.y += b.y; a.z += b.z; a.w += b.w;
  }
  const int row = i >> 7;
  const float inv = 1.f / lvec[row];
  const float4 h = ((const float4*)Hres)[i];
  float4 o;
  o.x = a.x * inv + h.x;
  o.y = a.y * inv + h.y;
  o.z = a.z * inv + h.z;
  o.w = a.w * inv + h.w;
  ((float4*)out)[i] = o;
}

// ---------------------------------------------------------------------------
extern "C" void kernel_launch(void* const* d_in, const int* in_sizes, int n_in,
                              void* d_out, int out_size, void* d_ws, size_t ws_size,
                              hipStream_t stream) {
  const float* H  = (const float*)d_in[0];
  const float* Wq = (const float*)d_in[1];
  const float* bq = (const float*)d_in[2];
  const float* Wk = (const float*)d_in[3];
  const float* bk = (const float*)d_in[4];
  float* out = (float*)d_out;

  const int N = 8192, D = 512;

  char* ws = (char*)d_ws;
  size_t off = 0;
  auto alloc = [&](size_t bytes) { char* p = ws + off; off += bytes; return p; };
  unsigned short* Hb   = (unsigned short*)alloc((size_t)N * D * 2);       // 8 MB
  unsigned char*  HbT8 = (unsigned char*)alloc((size_t)D * N);            // 4.2 MB
  unsigned char*  QK8  = (unsigned char*)alloc((size_t)N * 2 * D);        // 8.4 MB
  unsigned short* BqkT = (unsigned short*)alloc((size_t)2 * D * D * 2);   // 1 MB
  float* bqk = (float*)alloc((size_t)2 * D * 4);
  float* l   = (float*)alloc((size_t)N * 4);
  const size_t base = off;
  unsigned char* P8 = (unsigned char*)(ws + base);

  const size_t pBytes = (size_t)N * N;                   // 67 MB (fp8)
  const size_t partBytes = (size_t)N * D * 4;            // 16.8 MB each
  const size_t partStride = (size_t)N * D;               // floats
  const size_t avail = (ws_size > base) ? (ws_size - base) : 0;

  int S = 0;
  if (avail >= pBytes) {
    const size_t extra = avail - pBytes;
    S = (extra >= 2 * partBytes) ? 2 : 1;   // S=2 beats 4: half the partial HBM traffic
  }
  float* parts = (float*)(ws + base + pBytes);

  // --- prep ---
  hipMemsetAsync(l, 0, (size_t)N * 4, stream);
  transpose_h_kernel<<<dim3(D / 64, N / 64), 256, 0, stream>>>(H, HbT8, Hb, N, D);
  transpose_w_kernel<<<dim3(D / 64, D / 64), 256, 0, stream>>>(Wq, BqkT, D, D);
  transpose_w_kernel<<<dim3(D / 64, D / 64), 256, 0, stream>>>(Wk, BqkT + (size_t)D * D, D, D);
  pack_bias_kernel<<<dim3(4), 256, 0, stream>>>(bq, bk, bqk);

  // --- merged Q|K projection -> fp8: QK8[8192][1024] ---
  gemm_proj<<<dim3(2 * D / 128, N / 128), 256, 0, stream>>>(
      Hb, BqkT, 2 * D, D, bqk, QK8);

  if (S >= 1) {
    // scores: P8 = fp8(exp(diag0(Q K^T)*scale)), fused row-sums into l
    gemm_qk8<<<dim3(N / 128, N / 128), 512, 0, stream>>>(
        QK8, QK8 + D, N, D, 2 * D, 2 * D, l, 0, P8);
    if (S == 1) {
      gemm_pv8<true><<<dim3(D / 128, N / 64, 1), 256, 0, stream>>>(
          P8, HbT8, N, l, H, 0, out, 0);
    } else {
      gemm_pv8<false><<<dim3(D / 128, N / 64, S), 256, 0, stream>>>(
          P8, HbT8, N / S, nullptr, nullptr, 0, parts, partStride);
      combine_kernel<<<dim3((N * D / 4 + 255) / 256), 256, 0, stream>>>(
          parts, partStride, S, l, H, out, N * D / 4);
    }
  } else {
    // ws too small for full P8: chunk rows (direct PV per chunk)
    int maxRows = (int)(avail / (size_t)N);
    maxRows &= ~127;
    if (maxRows < 128) maxRows = 128;
    for (int r0 = 0; r0 < N; r0 += maxRows) {
      int rows = N - r0;
      if (rows > maxRows) rows = maxRows;
      gemm_qk8<<<dim3(N / 128, rows / 128), 512, 0, stream>>>(
          QK8 + (size_t)r0 * 2 * D, QK8 + D, N, D, 2 * D, 2 * D, l, r0, P8);
      gemm_pv8<true><<<dim3(D / 128, rows / 64, 1), 256, 0, stream>>>(
          P8, HbT8, N, l, H, r0, out, 0);
    }
  }
}

// Round 9
// 269.121 us; speedup vs baseline: 1.1267x; 1.0021x over previous
//
#include <hip/hip_runtime.h>
#include <cstdint>
#include <cstddef>

#define GLOBAL_AS __attribute__((address_space(1)))
#define LDS_AS __attribute__((address_space(3)))

typedef __attribute__((ext_vector_type(8))) short short8;
typedef __attribute__((ext_vector_type(4))) float floatx4;
typedef __attribute__((ext_vector_type(4))) int int4v;
typedef __attribute__((ext_vector_type(8))) int int8v;

#if defined(__has_builtin)
#if __has_builtin(__builtin_amdgcn_cvt_pk_fp8_f32)
#define HAVE_HW_FP8 1
#endif
#endif

static __device__ __forceinline__ unsigned short f2bf(float f) {
  uint32_t u = __builtin_bit_cast(uint32_t, f);
  u += 0x7fffu + ((u >> 16) & 1u);
  return (unsigned short)(u >> 16);
}

// OCP e4m3 encode (RNE, saturate to 448)
static __device__ __forceinline__ unsigned char f2fp8(float f) {
#ifdef HAVE_HW_FP8
  float c = fminf(fmaxf(f, -448.f), 448.f);
  return (unsigned char)(__builtin_amdgcn_cvt_pk_fp8_f32(c, 0.f, 0, false) & 0xff);
#else
  unsigned char s = 0;
  if (f < 0.f) { s = 0x80; f = -f; }
  if (f >= 448.f) return s | 0x7e;
  if (f < 0.015625f) { int r = (int)(f * 512.f + 0.5f); return s | (unsigned char)r; }
  uint32_t u = __builtin_bit_cast(uint32_t, f);
  int e = (int)((u >> 23) & 0xff) - 127;
  uint32_t keep = (u >> 20) & 7, rest = u & 0xfffffu;
  if (rest > 0x80000u || (rest == 0x80000u && (keep & 1))) ++keep;
  if (keep == 8) { keep = 0; ++e; }
  if (e > 8) return s | 0x7e;
  return s | (unsigned char)(((e + 7) << 3) | keep);
#endif
}

// pack 4 fp8 bytes (cols l15+{0,16,32,48}) into one dword, bytes in j order
static __device__ __forceinline__ uint32_t pack4fp8(const float e[4]) {
#ifdef HAVE_HW_FP8
  const uint32_t p01 = (uint32_t)__builtin_amdgcn_cvt_pk_fp8_f32(e[0], e[1], 0, false);
  const uint32_t p23 = (uint32_t)__builtin_amdgcn_cvt_pk_fp8_f32(e[2], e[3], 0, false);
  return (p01 & 0xffffu) | (p23 << 16);
#else
  return (uint32_t)f2fp8(e[0]) | ((uint32_t)f2fp8(e[1]) << 8) |
         ((uint32_t)f2fp8(e[2]) << 16) | ((uint32_t)f2fp8(e[3]) << 24);
#endif
}

// Transpose lane-local stride-16 byte layout into a coalesced dword.
static __device__ __forceinline__ uint32_t gather_dword(uint32_t w, int quad, int l15) {
  const int src = quad * 16 + 4 * (l15 & 3);
  const int sh = (l15 >> 2) * 8;
  const uint32_t v0 = (uint32_t)__shfl((int)w, src);
  const uint32_t v1 = (uint32_t)__shfl((int)w, src + 1);
  const uint32_t v2 = (uint32_t)__shfl((int)w, src + 2);
  const uint32_t v3 = (uint32_t)__shfl((int)w, src + 3);
  return ((v0 >> sh) & 0xffu) | (((v1 >> sh) & 0xffu) << 8) |
         (((v2 >> sh) & 0xffu) << 16) | (((v3 >> sh) & 0xffu) << 24);
}

static __device__ __forceinline__ void wait_vm0() {
  __builtin_amdgcn_s_waitcnt(0x0f70);  // vmcnt(0)
}

// ---------------------------------------------------------------------------
// MX helpers: BK=128 fp8 K-loop. LDS row = 128 B (8 chunks of 16 B); chunk c
// of row r stored at r*128 + ((c ^ (r&7))*16) — XOR swizzle gives
// conflict-free b128 reads (8 start-groups x 4 banks = 32 banks/phase).
// MFMA: mfma_scale_f32_16x16x128_f8f6f4, fmt fp8/fp8, scale E8M0=127 (=1.0)
// -> arithmetic identical to non-scaled e4m3 path.
// K-permutation: lane (row=l15, quad) covers k-chunks {2q, 2q+1}; A and B use
// the same mapping so the contraction is exact.
// ---------------------------------------------------------------------------
static __device__ __forceinline__ int8v load_frag32(const unsigned char* base, int row, int quad) {
  const int h = row & 7;
  const int c0 = (2 * quad) ^ h;
  const int c1 = (2 * quad + 1) ^ h;
  const int4v lo = *(const int4v*)(base + row * 128 + c0 * 16);
  const int4v hi = *(const int4v*)(base + row * 128 + c1 * 16);
  int8v r;
  r[0] = lo[0]; r[1] = lo[1]; r[2] = lo[2]; r[3] = lo[3];
  r[4] = hi[0]; r[5] = hi[1]; r[6] = hi[2]; r[7] = hi[3];
  return r;
}

static __device__ __forceinline__ floatx4 mx_mfma(int8v a, int8v b, floatx4 c) {
  // (a, b, c, cbsz=fp8, blgp=fp8, opsel_a, scale_a, opsel_b, scale_b)
  return __builtin_amdgcn_mfma_scale_f32_16x16x128_f8f6f4(a, b, c, 0, 0, 0, 0x7f, 0, 0x7f);
}

// ---------------------------------------------------------------------------
// Transpose H: fp32 [R][C] -> HbT8 fp8 [C][R], plus straight bf16 copy [R][C]
// ---------------------------------------------------------------------------
__global__ __launch_bounds__(256) void transpose_h_kernel(
    const float* __restrict__ in, unsigned char* __restrict__ outT8,
    unsigned short* __restrict__ outN, int R, int C) {
  __shared__ float t[64][65];
  const int bc = blockIdx.x * 64;
  const int br = blockIdx.y * 64;
  const int tc = threadIdx.x & 63;
  const int tr = threadIdx.x >> 6;
  for (int r = tr; r < 64; r += 4) {
    const float v = in[(size_t)(br + r) * C + bc + tc];
    t[r][tc] = v;
    outN[(size_t)(br + r) * C + bc + tc] = f2bf(v);
  }
  __syncthreads();
  for (int r = tr; r < 64; r += 4)
    outT8[(size_t)(bc + r) * R + br + tc] = f2fp8(t[tc][r]);
}

// Transpose weights: fp32 [R][C] -> bf16 [C][R]
__global__ __launch_bounds__(256) void transpose_w_kernel(
    const float* __restrict__ in, unsigned short* __restrict__ outT, int R, int C) {
  __shared__ float t[64][65];
  const int bc = blockIdx.x * 64;
  const int br = blockIdx.y * 64;
  const int tc = threadIdx.x & 63;
  const int tr = threadIdx.x >> 6;
  for (int r = tr; r < 64; r += 4)
    t[r][tc] = in[(size_t)(br + r) * C + bc + tc];
  __syncthreads();
  for (int r = tr; r < 64; r += 4)
    outT[(size_t)(bc + r) * R + br + tc] = f2bf(t[tc][r]);
}

__global__ __launch_bounds__(256) void pack_bias_kernel(
    const float* __restrict__ bq, const float* __restrict__ bk,
    float* __restrict__ bqk) {
  int i = blockIdx.x * 256 + threadIdx.x;
  bqk[i] = (i < 512) ? bq[i] : bk[i - 512];
}

// ---------------------------------------------------------------------------
// Projection GEMM (bf16 x bf16 -> fp8): QK8[m][n] = fp8(A[m][k]*Bt[n][k]+b[n])
// 128x128 tile, BK=32, double-buffered one-barrier K-loop. (unchanged r8)
// ---------------------------------------------------------------------------
__global__ __launch_bounds__(256, 4) void gemm_proj(
    const unsigned short* __restrict__ A,    // Hb [8192][512] bf16
    const unsigned short* __restrict__ Bt,   // BqkT [1024][512] bf16
    int Ncols, int K,
    const float* __restrict__ bias,
    unsigned char* __restrict__ C8)          // QK8 [8192][1024] fp8
{
  __shared__ unsigned short As[2][128 * 32];
  __shared__ unsigned short Bs[2][128 * 32];

  const int tid  = threadIdx.x;
  const int lane = tid & 63;
  const int wave = tid >> 6;
  const int wr   = (wave >> 1) * 64;
  const int wc   = (wave & 1) * 64;
  const int quad = lane >> 4;
  const int l15  = lane & 15;
  const int bm   = blockIdx.y * 128;
  const int bn   = blockIdx.x * 128;

  const int c0 = tid, c1 = tid + 256;
  const int r0a = c0 >> 2, k0a = (c0 & 3) << 3;
  const int r1a = c1 >> 2, k1a = (c1 & 3) << 3;

  auto stage = [&](int kt, int b) {
    __builtin_amdgcn_global_load_lds(
        (const GLOBAL_AS void*)(A + (size_t)(bm + r0a) * K + kt + k0a),
        (LDS_AS void*)(&As[b][c0 * 8]), 16, 0, 0);
    __builtin_amdgcn_global_load_lds(
        (const GLOBAL_AS void*)(A + (size_t)(bm + r1a) * K + kt + k1a),
        (LDS_AS void*)(&As[b][c1 * 8]), 16, 0, 0);
    __builtin_amdgcn_global_load_lds(
        (const GLOBAL_AS void*)(Bt + (size_t)(bn + r0a) * K + kt + k0a),
        (LDS_AS void*)(&Bs[b][c0 * 8]), 16, 0, 0);
    __builtin_amdgcn_global_load_lds(
        (const GLOBAL_AS void*)(Bt + (size_t)(bn + r1a) * K + kt + k1a),
        (LDS_AS void*)(&Bs[b][c1 * 8]), 16, 0, 0);
  };

  floatx4 acc[4][4];
#pragma unroll
  for (int i = 0; i < 4; ++i)
#pragma unroll
    for (int j = 0; j < 4; ++j)
      acc[i][j] = (floatx4){0.f, 0.f, 0.f, 0.f};

  stage(0, 0);
  const int nIter = K >> 5;
  for (int it = 0; it < nIter; ++it) {
    const int b = it & 1;
    wait_vm0();
    __syncthreads();
    if (it + 1 < nIter) stage((it + 1) << 5, b ^ 1);

    short8 af[4], bfr[4];
#pragma unroll
    for (int i = 0; i < 4; ++i)
      af[i] = *(const short8*)(&As[b][(wr + i * 16 + l15) * 32 + quad * 8]);
#pragma unroll
    for (int j = 0; j < 4; ++j)
      bfr[j] = *(const short8*)(&Bs[b][(wc + j * 16 + l15) * 32 + quad * 8]);
#pragma unroll
    for (int i = 0; i < 4; ++i)
#pragma unroll
      for (int j = 0; j < 4; ++j)
        acc[i][j] = __builtin_amdgcn_mfma_f32_16x16x32_bf16(af[i], bfr[j], acc[i][j], 0, 0, 0);
  }

  // epilogue — C/D layout: col = lane&15, row = quad*4 + reg
#pragma unroll
  for (int i = 0; i < 4; ++i) {
    const int rl = bm + wr + i * 16 + quad * 4;
#pragma unroll
    for (int r = 0; r < 4; ++r) {
      const int row = rl + r;
      float e[4];
#pragma unroll
      for (int j = 0; j < 4; ++j)
        e[j] = acc[i][j][r] + bias[bn + wc + j * 16 + l15];
      const uint32_t d = gather_dword(pack4fp8(e), quad, l15);
      *(uint32_t*)(C8 + (size_t)row * Ncols + bn + wc + 4 * l15) = d;
    }
  }
}

// ---------------------------------------------------------------------------
// Scores GEMM, MX fp8: P8 = fp8(exp(diag0(Q K^T)*scale)), fused row-sums.
// 128x128 tile, BK=128, 512 threads / 8 waves (wave-tile 32x64, acc[2][4]),
// double-buffered one-barrier loop, 4 K-iters. LDS 64 KB -> 2 blocks/CU.
// ---------------------------------------------------------------------------
__global__ __launch_bounds__(512, 4) void gemm_qk8(
    const unsigned char* __restrict__ A,     // Q8 rows [.][lda] fp8
    const unsigned char* __restrict__ Bt,    // K8 [8192][ldb] fp8
    int Ncols, int K, int lda, int ldb,
    float* __restrict__ lsum,
    int row0,
    unsigned char* __restrict__ P8)
{
  __shared__ unsigned char As[2][128 * 128];  // 16 KiB x2
  __shared__ unsigned char Bs[2][128 * 128];  // 16 KiB x2

  const int tid  = threadIdx.x;
  const int lane = tid & 63;
  const int wave = tid >> 6;           // 0..7
  const int wr   = (wave >> 1) * 32;   // 0,32,64,96
  const int wc   = (wave & 1) * 64;    // 0,64
  const int quad = lane >> 4;
  const int l15  = lane & 15;
  const int bm   = blockIdx.y * 128;
  const int bn   = blockIdx.x * 128;

  // staging: 1024 chunks of 16B per matrix; chunk L -> row L>>3, swizzled col
  const int L0 = tid, L1 = tid + 512;
  const int sr0 = L0 >> 3, sc0 = ((L0 & 7) ^ (sr0 & 7)) << 4;
  const int sr1 = L1 >> 3, sc1 = ((L1 & 7) ^ (sr1 & 7)) << 4;

  auto stage = [&](int kt, int b) {
    __builtin_amdgcn_global_load_lds(
        (const GLOBAL_AS void*)(A + (size_t)(bm + sr0) * lda + kt + sc0),
        (LDS_AS void*)(&As[b][L0 * 16]), 16, 0, 0);
    __builtin_amdgcn_global_load_lds(
        (const GLOBAL_AS void*)(A + (size_t)(bm + sr1) * lda + kt + sc1),
        (LDS_AS void*)(&As[b][L1 * 16]), 16, 0, 0);
    __builtin_amdgcn_global_load_lds(
        (const GLOBAL_AS void*)(Bt + (size_t)(bn + sr0) * ldb + kt + sc0),
        (LDS_AS void*)(&Bs[b][L0 * 16]), 16, 0, 0);
    __builtin_amdgcn_global_load_lds(
        (const GLOBAL_AS void*)(Bt + (size_t)(bn + sr1) * ldb + kt + sc1),
        (LDS_AS void*)(&Bs[b][L1 * 16]), 16, 0, 0);
  };

  floatx4 acc[2][4];
#pragma unroll
  for (int i = 0; i < 2; ++i)
#pragma unroll
    for (int j = 0; j < 4; ++j)
      acc[i][j] = (floatx4){0.f, 0.f, 0.f, 0.f};

  stage(0, 0);
  const int nIter = K >> 7;   // 4
  for (int it = 0; it < nIter; ++it) {
    const int b = it & 1;
    wait_vm0();
    __syncthreads();
    if (it + 1 < nIter) stage((it + 1) << 7, b ^ 1);

    const int8v af0 = load_frag32(As[b], wr + l15, quad);
    const int8v af1 = load_frag32(As[b], wr + 16 + l15, quad);
#pragma unroll
    for (int j = 0; j < 4; ++j) {
      const int8v bf = load_frag32(Bs[b], wc + j * 16 + l15, quad);
      acc[0][j] = mx_mfma(af0, bf, acc[0][j]);
      acc[1][j] = mx_mfma(af1, bf, acc[1][j]);
    }
  }

  const float scale = 0.044194173824159216f;  // 1/sqrt(512)
#pragma unroll
  for (int i = 0; i < 2; ++i) {
    const int rl = bm + wr + i * 16 + quad * 4;
#pragma unroll
    for (int r = 0; r < 4; ++r) {
      const int row = rl + r;
      float e[4];
#pragma unroll
      for (int j = 0; j < 4; ++j) {
        const int col = bn + wc + j * 16 + l15;
        const float lg = ((row0 + row) == col) ? 0.f : acc[i][j][r] * scale;
        e[j] = fminf(__expf(lg), 448.f);
      }
      float rsum = (e[0] + e[1]) + (e[2] + e[3]);
      const uint32_t d = gather_dword(pack4fp8(e), quad, l15);
      *(uint32_t*)(P8 + (size_t)row * Ncols + bn + wc + 4 * l15) = d;
      rsum += __shfl_xor(rsum, 1);
      rsum += __shfl_xor(rsum, 2);
      rsum += __shfl_xor(rsum, 4);
      rsum += __shfl_xor(rsum, 8);
      if (l15 == 0) atomicAdd(&lsum[row0 + row], rsum);
    }
  }
}

// ---------------------------------------------------------------------------
// PV GEMM, MX fp8: O[m][n] = sum_k P8[m][k]*HbT8[n][k]. 64x128 tile, BK=128,
// double-buffered, split-K over z. LDS 48 KB -> 3 blocks/CU.
// ---------------------------------------------------------------------------
template <bool DIRECT>
__global__ __launch_bounds__(256, 3) void gemm_pv8(
    const unsigned char* __restrict__ P,     // [rows][8192] fp8 (chunk base)
    const unsigned char* __restrict__ Bt,    // HbT8 [512][8192] fp8
    int Kchunk,
    const float* __restrict__ lvec,
    const float* __restrict__ Hres,
    int row0,
    float* __restrict__ outp,
    size_t partStride)
{
  __shared__ unsigned char As[2][64 * 128];   // 8 KiB x2
  __shared__ unsigned char Bs[2][128 * 128];  // 16 KiB x2

  const int tid  = threadIdx.x;
  const int lane = tid & 63;
  const int wave = tid >> 6;
  const int wr   = (wave >> 1) * 32;
  const int wc   = (wave & 1) * 64;
  const int quad = lane >> 4;
  const int l15  = lane & 15;
  const int bm   = blockIdx.y * 64;
  const int bn   = blockIdx.x * 128;
  const int k0   = blockIdx.z * Kchunk;

  float* part = outp + (DIRECT ? 0 : (size_t)blockIdx.z * partStride);

  // A: 512 chunks (64 rows x 128B); B: 1024 chunks (128 rows x 128B)
  const int a0 = tid, a1 = tid + 256;
  const int ar0 = a0 >> 3, ac0 = ((a0 & 7) ^ (ar0 & 7)) << 4;
  const int ar1 = a1 >> 3, ac1 = ((a1 & 7) ^ (ar1 & 7)) << 4;
  const int b0 = tid, b1 = tid + 256, b2 = tid + 512, b3 = tid + 768;
  const int br0 = b0 >> 3, bc0 = ((b0 & 7) ^ (br0 & 7)) << 4;
  const int br1 = b1 >> 3, bc1 = ((b1 & 7) ^ (br1 & 7)) << 4;
  const int br2 = b2 >> 3, bc2 = ((b2 & 7) ^ (br2 & 7)) << 4;
  const int br3 = b3 >> 3, bc3 = ((b3 & 7) ^ (br3 & 7)) << 4;

  auto stage = [&](int kt, int b) {
    __builtin_amdgcn_global_load_lds(
        (const GLOBAL_AS void*)(P + (size_t)(bm + ar0) * 8192 + kt + ac0),
        (LDS_AS void*)(&As[b][a0 * 16]), 16, 0, 0);
    __builtin_amdgcn_global_load_lds(
        (const GLOBAL_AS void*)(P + (size_t)(bm + ar1) * 8192 + kt + ac1),
        (LDS_AS void*)(&As[b][a1 * 16]), 16, 0, 0);
    __builtin_amdgcn_global_load_lds(
        (const GLOBAL_AS void*)(Bt + (size_t)(bn + br0) * 8192 + kt + bc0),
        (LDS_AS void*)(&Bs[b][b0 * 16]), 16, 0, 0);
    __builtin_amdgcn_global_load_lds(
        (const GLOBAL_AS void*)(Bt + (size_t)(bn + br1) * 8192 + kt + bc1),
        (LDS_AS void*)(&Bs[b][b1 * 16]), 16, 0, 0);
    __builtin_amdgcn_global_load_lds(
        (const GLOBAL_AS void*)(Bt + (size_t)(bn + br2) * 8192 + kt + bc2),
        (LDS_AS void*)(&Bs[b][b2 * 16]), 16, 0, 0);
    __builtin_amdgcn_global_load_lds(
        (const GLOBAL_AS void*)(Bt + (size_t)(bn + br3) * 8192 + kt + bc3),
        (LDS_AS void*)(&Bs[b][b3 * 16]), 16, 0, 0);
  };

  floatx4 acc[2][4];
#pragma unroll
  for (int i = 0; i < 2; ++i)
#pragma unroll
    for (int j = 0; j < 4; ++j)
      acc[i][j] = (floatx4){0.f, 0.f, 0.f, 0.f};

  stage(k0, 0);
  const int nIter = Kchunk >> 7;
  for (int it = 0; it < nIter; ++it) {
    const int b = it & 1;
    wait_vm0();
    __syncthreads();
    if (it + 1 < nIter) stage(k0 + ((it + 1) << 7), b ^ 1);

    const int8v af0 = load_frag32(As[b], wr + l15, quad);
    const int8v af1 = load_frag32(As[b], wr + 16 + l15, quad);
#pragma unroll
    for (int j = 0; j < 4; ++j) {
      const int8v bf = load_frag32(Bs[b], wc + j * 16 + l15, quad);
      acc[0][j] = mx_mfma(af0, bf, acc[0][j]);
      acc[1][j] = mx_mfma(af1, bf, acc[1][j]);
    }
  }

#pragma unroll
  for (int i = 0; i < 2; ++i) {
    const int rl = bm + wr + i * 16 + quad * 4;
#pragma unroll
    for (int j = 0; j < 4; ++j) {
      const int col = bn + wc + j * 16 + l15;
#pragma unroll
      for (int r = 0; r < 4; ++r) {
        const int row = rl + r;
        const float v = acc[i][j][r];
        if (DIRECT) {
          const int grow = row0 + row;
          part[(size_t)grow * 512 + col] =
              v / lvec[grow] + Hres[(size_t)grow * 512 + col];
        } else {
          part[(size_t)row * 512 + col] = v;
        }
      }
    }
  }
}

// combine: out = (sum_s partial_s) / l[row] + H
__global__ __launch_bounds__(256) void combine_kernel(
    const float* __restrict__ parts, size_t partStride, int S,
    const float* __restrict__ lvec, const float* __restrict__ Hres,
    float* __restrict__ out, int n4) {
  int i = blockIdx.x * 256 + threadIdx.x;
  if (i >= n4) return;
  float4 a = ((const float4*)parts)[i];
  for (int s = 1; s < S; ++s) {
    const float4 b = ((const float4*)(parts + (size_t)s * partStride))[i];
    a.x += b.x; a.y += b.y; a.z += b.z; a.w += b.w;
  }
  const int row = i >> 7;
  const float inv = 1.f / lvec[row];
  const float4 h = ((const float4*)Hres)[i];
  float4 o;
  o.x = a.x * inv + h.x;
  o.y = a.y * inv + h.y;
  o.z = a.z * inv + h.z;
  o.w = a.w * inv + h.w;
  ((float4*)out)[i] = o;
}

// ---------------------------------------------------------------------------
extern "C" void kernel_launch(void* const* d_in, const int* in_sizes, int n_in,
                              void* d_out, int out_size, void* d_ws, size_t ws_size,
                              hipStream_t stream) {
  const float* H  = (const float*)d_in[0];
  const float* Wq = (const float*)d_in[1];
  const float* bq = (const float*)d_in[2];
  const float* Wk = (const float*)d_in[3];
  const float* bk = (const float*)d_in[4];
  float* out = (float*)d_out;

  const int N = 8192, D = 512;

  char* ws = (char*)d_ws;
  size_t off = 0;
  auto alloc = [&](size_t bytes) { char* p = ws + off; off += bytes; return p; };
  unsigned short* Hb   = (unsigned short*)alloc((size_t)N * D * 2);       // 8 MB
  unsigned char*  HbT8 = (unsigned char*)alloc((size_t)D * N);            // 4.2 MB
  unsigned char*  QK8  = (unsigned char*)alloc((size_t)N * 2 * D);        // 8.4 MB
  unsigned short* BqkT = (unsigned short*)alloc((size_t)2 * D * D * 2);   // 1 MB
  float* bqk = (float*)alloc((size_t)2 * D * 4);
  float* l   = (float*)alloc((size_t)N * 4);
  const size_t base = off;
  unsigned char* P8 = (unsigned char*)(ws + base);

  const size_t pBytes = (size_t)N * N;                   // 67 MB (fp8)
  const size_t partBytes = (size_t)N * D * 4;            // 16.8 MB each
  const size_t partStride = (size_t)N * D;               // floats
  const size_t avail = (ws_size > base) ? (ws_size - base) : 0;

  int S = 0;
  if (avail >= pBytes) {
    const size_t extra = avail - pBytes;
    S = (extra >= 2 * partBytes) ? 2 : 1;   // S=2: half the partial HBM traffic of 4
  }
  float* parts = (float*)(ws + base + pBytes);

  // --- prep ---
  hipMemsetAsync(l, 0, (size_t)N * 4, stream);
  transpose_h_kernel<<<dim3(D / 64, N / 64), 256, 0, stream>>>(H, HbT8, Hb, N, D);
  transpose_w_kernel<<<dim3(D / 64, D / 64), 256, 0, stream>>>(Wq, BqkT, D, D);
  transpose_w_kernel<<<dim3(D / 64, D / 64), 256, 0, stream>>>(Wk, BqkT + (size_t)D * D, D, D);
  pack_bias_kernel<<<dim3(4), 256, 0, stream>>>(bq, bk, bqk);

  // --- merged Q|K projection -> fp8: QK8[8192][1024] ---
  gemm_proj<<<dim3(2 * D / 128, N / 128), 256, 0, stream>>>(
      Hb, BqkT, 2 * D, D, bqk, QK8);

  if (S >= 1) {
    // scores: P8 = fp8(exp(diag0(Q K^T)*scale)), fused row-sums into l
    gemm_qk8<<<dim3(N / 128, N / 128), 512, 0, stream>>>(
        QK8, QK8 + D, N, D, 2 * D, 2 * D, l, 0, P8);
    if (S == 1) {
      gemm_pv8<true><<<dim3(D / 128, N / 64, 1), 256, 0, stream>>>(
          P8, HbT8, N, l, H, 0, out, 0);
    } else {
      gemm_pv8<false><<<dim3(D / 128, N / 64, S), 256, 0, stream>>>(
          P8, HbT8, N / S, nullptr, nullptr, 0, parts, partStride);
      combine_kernel<<<dim3((N * D / 4 + 255) / 256), 256, 0, stream>>>(
          parts, partStride, S, l, H, out, N * D / 4);
    }
  } else {
    // ws too small for full P8: chunk rows (direct PV per chunk)
    int maxRows = (int)(avail / (size_t)N);
    maxRows &= ~127;
    if (maxRows < 128) maxRows = 128;
    for (int r0 = 0; r0 < N; r0 += maxRows) {
      int rows = N - r0;
      if (rows > maxRows) rows = maxRows;
      gemm_qk8<<<dim3(N / 128, rows / 128), 512, 0, stream>>>(
          QK8 + (size_t)r0 * 2 * D, QK8 + D, N, D, 2 * D, 2 * D, l, r0, P8);
      gemm_pv8<true><<<dim3(D / 128, rows / 64, 1), 256, 0, stream>>>(
          P8, HbT8, N, l, H, r0, out, 0);
    }
  }
}

// Round 10
// 261.350 us; speedup vs baseline: 1.1602x; 1.0297x over previous
//
#include <hip/hip_runtime.h>
#include <cstdint>
#include <cstddef>

#define GLOBAL_AS __attribute__((address_space(1)))
#define LDS_AS __attribute__((address_space(3)))

typedef __attribute__((ext_vector_type(8))) short short8;
typedef __attribute__((ext_vector_type(4))) float floatx4;
typedef __attribute__((ext_vector_type(2))) long long2v;   // 16B LDS read
typedef __attribute__((ext_vector_type(4))) int int4v;
typedef __attribute__((ext_vector_type(8))) int int8v;

#if defined(__has_builtin)
#if __has_builtin(__builtin_amdgcn_cvt_pk_fp8_f32)
#define HAVE_HW_FP8 1
#endif
#endif

static __device__ __forceinline__ unsigned short f2bf(float f) {
  uint32_t u = __builtin_bit_cast(uint32_t, f);
  u += 0x7fffu + ((u >> 16) & 1u);
  return (unsigned short)(u >> 16);
}

// OCP e4m3 encode (RNE, saturate to 448)
static __device__ __forceinline__ unsigned char f2fp8(float f) {
#ifdef HAVE_HW_FP8
  float c = fminf(fmaxf(f, -448.f), 448.f);
  return (unsigned char)(__builtin_amdgcn_cvt_pk_fp8_f32(c, 0.f, 0, false) & 0xff);
#else
  unsigned char s = 0;
  if (f < 0.f) { s = 0x80; f = -f; }
  if (f >= 448.f) return s | 0x7e;
  if (f < 0.015625f) { int r = (int)(f * 512.f + 0.5f); return s | (unsigned char)r; }
  uint32_t u = __builtin_bit_cast(uint32_t, f);
  int e = (int)((u >> 23) & 0xff) - 127;
  uint32_t keep = (u >> 20) & 7, rest = u & 0xfffffu;
  if (rest > 0x80000u || (rest == 0x80000u && (keep & 1))) ++keep;
  if (keep == 8) { keep = 0; ++e; }
  if (e > 8) return s | 0x7e;
  return s | (unsigned char)(((e + 7) << 3) | keep);
#endif
}

// pack 4 fp8 bytes (cols l15+{0,16,32,48}) into one dword, bytes in j order
static __device__ __forceinline__ uint32_t pack4fp8(const float e[4]) {
#ifdef HAVE_HW_FP8
  const uint32_t p01 = (uint32_t)__builtin_amdgcn_cvt_pk_fp8_f32(e[0], e[1], 0, false);
  const uint32_t p23 = (uint32_t)__builtin_amdgcn_cvt_pk_fp8_f32(e[2], e[3], 0, false);
  return (p01 & 0xffffu) | (p23 << 16);
#else
  return (uint32_t)f2fp8(e[0]) | ((uint32_t)f2fp8(e[1]) << 8) |
         ((uint32_t)f2fp8(e[2]) << 16) | ((uint32_t)f2fp8(e[3]) << 24);
#endif
}

// Transpose lane-local stride-16 byte layout into a coalesced dword.
static __device__ __forceinline__ uint32_t gather_dword(uint32_t w, int quad, int l15) {
  const int src = quad * 16 + 4 * (l15 & 3);
  const int sh = (l15 >> 2) * 8;
  const uint32_t v0 = (uint32_t)__shfl((int)w, src);
  const uint32_t v1 = (uint32_t)__shfl((int)w, src + 1);
  const uint32_t v2 = (uint32_t)__shfl((int)w, src + 2);
  const uint32_t v3 = (uint32_t)__shfl((int)w, src + 3);
  return ((v0 >> sh) & 0xffu) | (((v1 >> sh) & 0xffu) << 8) |
         (((v2 >> sh) & 0xffu) << 16) | (((v3 >> sh) & 0xffu) << 24);
}

static __device__ __forceinline__ void wait_vm0() {
  __builtin_amdgcn_s_waitcnt(0x0f70);  // vmcnt(0)
}

// ---------------------------------------------------------------------------
// MX helpers (pv8 only): BK=128 fp8. LDS row = 128 B (8 chunks of 16 B);
// chunk c of row r stored at r*128 + ((c ^ (r&7))*16) — conflict-free b128.
// scale E8M0=127 (=1.0) -> arithmetic identical to non-scaled e4m3.
// ---------------------------------------------------------------------------
static __device__ __forceinline__ int8v load_frag32(const unsigned char* base, int row, int quad) {
  const int h = row & 7;
  const int c0 = (2 * quad) ^ h;
  const int c1 = (2 * quad + 1) ^ h;
  const int4v lo = *(const int4v*)(base + row * 128 + c0 * 16);
  const int4v hi = *(const int4v*)(base + row * 128 + c1 * 16);
  int8v r;
  r[0] = lo[0]; r[1] = lo[1]; r[2] = lo[2]; r[3] = lo[3];
  r[4] = hi[0]; r[5] = hi[1]; r[6] = hi[2]; r[7] = hi[3];
  return r;
}

static __device__ __forceinline__ floatx4 mx_mfma(int8v a, int8v b, floatx4 c) {
  return __builtin_amdgcn_mfma_scale_f32_16x16x128_f8f6f4(a, b, c, 0, 0, 0, 0x7f, 0, 0x7f);
}

// ---------------------------------------------------------------------------
// Transpose H: fp32 [R][C] -> HbT8 fp8 [C][R], plus straight bf16 copy [R][C]
// ---------------------------------------------------------------------------
__global__ __launch_bounds__(256) void transpose_h_kernel(
    const float* __restrict__ in, unsigned char* __restrict__ outT8,
    unsigned short* __restrict__ outN, int R, int C) {
  __shared__ float t[64][65];
  const int bc = blockIdx.x * 64;
  const int br = blockIdx.y * 64;
  const int tc = threadIdx.x & 63;
  const int tr = threadIdx.x >> 6;
  for (int r = tr; r < 64; r += 4) {
    const float v = in[(size_t)(br + r) * C + bc + tc];
    t[r][tc] = v;
    outN[(size_t)(br + r) * C + bc + tc] = f2bf(v);
  }
  __syncthreads();
  for (int r = tr; r < 64; r += 4)
    outT8[(size_t)(bc + r) * R + br + tc] = f2fp8(t[tc][r]);
}

// Transpose weights: fp32 [R][C] -> bf16 [C][R]
__global__ __launch_bounds__(256) void transpose_w_kernel(
    const float* __restrict__ in, unsigned short* __restrict__ outT, int R, int C) {
  __shared__ float t[64][65];
  const int bc = blockIdx.x * 64;
  const int br = blockIdx.y * 64;
  const int tc = threadIdx.x & 63;
  const int tr = threadIdx.x >> 6;
  for (int r = tr; r < 64; r += 4)
    t[r][tc] = in[(size_t)(br + r) * C + bc + tc];
  __syncthreads();
  for (int r = tr; r < 64; r += 4)
    outT[(size_t)(bc + r) * R + br + tc] = f2bf(t[tc][r]);
}

__global__ __launch_bounds__(256) void pack_bias_kernel(
    const float* __restrict__ bq, const float* __restrict__ bk,
    float* __restrict__ bqk) {
  int i = blockIdx.x * 256 + threadIdx.x;
  bqk[i] = (i < 512) ? bq[i] : bk[i - 512];
}

// ---------------------------------------------------------------------------
// Projection GEMM (bf16 x bf16 -> fp8): QK8[m][n] = fp8(A[m][k]*Bt[n][k]+b[n])
// 128x128 tile, BK=32, double-buffered one-barrier K-loop.
// ---------------------------------------------------------------------------
__global__ __launch_bounds__(256, 4) void gemm_proj(
    const unsigned short* __restrict__ A,    // Hb [8192][512] bf16
    const unsigned short* __restrict__ Bt,   // BqkT [1024][512] bf16
    int Ncols, int K,
    const float* __restrict__ bias,
    unsigned char* __restrict__ C8)          // QK8 [8192][1024] fp8
{
  __shared__ unsigned short As[2][128 * 32];
  __shared__ unsigned short Bs[2][128 * 32];

  const int tid  = threadIdx.x;
  const int lane = tid & 63;
  const int wave = tid >> 6;
  const int wr   = (wave >> 1) * 64;
  const int wc   = (wave & 1) * 64;
  const int quad = lane >> 4;
  const int l15  = lane & 15;
  const int bm   = blockIdx.y * 128;
  const int bn   = blockIdx.x * 128;

  const int c0 = tid, c1 = tid + 256;
  const int r0a = c0 >> 2, k0a = (c0 & 3) << 3;
  const int r1a = c1 >> 2, k1a = (c1 & 3) << 3;

  auto stage = [&](int kt, int b) {
    __builtin_amdgcn_global_load_lds(
        (const GLOBAL_AS void*)(A + (size_t)(bm + r0a) * K + kt + k0a),
        (LDS_AS void*)(&As[b][c0 * 8]), 16, 0, 0);
    __builtin_amdgcn_global_load_lds(
        (const GLOBAL_AS void*)(A + (size_t)(bm + r1a) * K + kt + k1a),
        (LDS_AS void*)(&As[b][c1 * 8]), 16, 0, 0);
    __builtin_amdgcn_global_load_lds(
        (const GLOBAL_AS void*)(Bt + (size_t)(bn + r0a) * K + kt + k0a),
        (LDS_AS void*)(&Bs[b][c0 * 8]), 16, 0, 0);
    __builtin_amdgcn_global_load_lds(
        (const GLOBAL_AS void*)(Bt + (size_t)(bn + r1a) * K + kt + k1a),
        (LDS_AS void*)(&Bs[b][c1 * 8]), 16, 0, 0);
  };

  floatx4 acc[4][4];
#pragma unroll
  for (int i = 0; i < 4; ++i)
#pragma unroll
    for (int j = 0; j < 4; ++j)
      acc[i][j] = (floatx4){0.f, 0.f, 0.f, 0.f};

  stage(0, 0);
  const int nIter = K >> 5;
  for (int it = 0; it < nIter; ++it) {
    const int b = it & 1;
    wait_vm0();
    __syncthreads();
    if (it + 1 < nIter) stage((it + 1) << 5, b ^ 1);

    short8 af[4], bfr[4];
#pragma unroll
    for (int i = 0; i < 4; ++i)
      af[i] = *(const short8*)(&As[b][(wr + i * 16 + l15) * 32 + quad * 8]);
#pragma unroll
    for (int j = 0; j < 4; ++j)
      bfr[j] = *(const short8*)(&Bs[b][(wc + j * 16 + l15) * 32 + quad * 8]);
#pragma unroll
    for (int i = 0; i < 4; ++i)
#pragma unroll
      for (int j = 0; j < 4; ++j)
        acc[i][j] = __builtin_amdgcn_mfma_f32_16x16x32_bf16(af[i], bfr[j], acc[i][j], 0, 0, 0);
  }

  // epilogue — C/D layout: col = lane&15, row = quad*4 + reg
#pragma unroll
  for (int i = 0; i < 4; ++i) {
    const int rl = bm + wr + i * 16 + quad * 4;
#pragma unroll
    for (int r = 0; r < 4; ++r) {
      const int row = rl + r;
      float e[4];
#pragma unroll
      for (int j = 0; j < 4; ++j)
        e[j] = acc[i][j][r] + bias[bn + wc + j * 16 + l15];
      const uint32_t d = gather_dword(pack4fp8(e), quad, l15);
      *(uint32_t*)(C8 + (size_t)row * Ncols + bn + wc + 4 * l15) = d;
    }
  }
}

// ---------------------------------------------------------------------------
// Scores GEMM fp8 x fp8 (r7 best-measured variant, 97.3 us): 128x128 tile,
// BK=64, 256 threads, acc[4][4], double-buffered one-barrier loop.
// K-permutation: lane fragment = one contiguous 16B ds_read_b128 at
// row*64 + quad*16. (256,4) is the register ceiling (56 VGPR + 64 AGPR).
// ---------------------------------------------------------------------------
__global__ __launch_bounds__(256, 4) void gemm_qk8(
    const unsigned char* __restrict__ A,     // Q8 rows [.][lda] fp8
    const unsigned char* __restrict__ Bt,    // K8 [8192][ldb] fp8
    int Ncols, int K, int lda, int ldb,
    float* __restrict__ lsum,
    int row0,
    unsigned char* __restrict__ P8)
{
  __shared__ unsigned char As[2][128 * 64];   // 8 KiB x2
  __shared__ unsigned char Bs[2][128 * 64];   // 8 KiB x2

  const int tid  = threadIdx.x;
  const int lane = tid & 63;
  const int wave = tid >> 6;
  const int wr   = (wave >> 1) * 64;
  const int wc   = (wave & 1) * 64;
  const int quad = lane >> 4;
  const int l15  = lane & 15;
  const int bm   = blockIdx.y * 128;
  const int bn   = blockIdx.x * 128;

  // staging: 512 chunks of 16B cover 128 rows x 64B
  const int c0 = tid, c1 = tid + 256;
  const int r0a = c0 >> 2, k0a = (c0 & 3) << 4;
  const int r1a = c1 >> 2, k1a = (c1 & 3) << 4;

  auto stage = [&](int kt, int b) {
    __builtin_amdgcn_global_load_lds(
        (const GLOBAL_AS void*)(A + (size_t)(bm + r0a) * lda + kt + k0a),
        (LDS_AS void*)(&As[b][c0 * 16]), 16, 0, 0);
    __builtin_amdgcn_global_load_lds(
        (const GLOBAL_AS void*)(A + (size_t)(bm + r1a) * lda + kt + k1a),
        (LDS_AS void*)(&As[b][c1 * 16]), 16, 0, 0);
    __builtin_amdgcn_global_load_lds(
        (const GLOBAL_AS void*)(Bt + (size_t)(bn + r0a) * ldb + kt + k0a),
        (LDS_AS void*)(&Bs[b][c0 * 16]), 16, 0, 0);
    __builtin_amdgcn_global_load_lds(
        (const GLOBAL_AS void*)(Bt + (size_t)(bn + r1a) * ldb + kt + k1a),
        (LDS_AS void*)(&Bs[b][c1 * 16]), 16, 0, 0);
  };

  floatx4 acc[4][4];
#pragma unroll
  for (int i = 0; i < 4; ++i)
#pragma unroll
    for (int j = 0; j < 4; ++j)
      acc[i][j] = (floatx4){0.f, 0.f, 0.f, 0.f};

  stage(0, 0);
  const int nIter = K >> 6;
  for (int it = 0; it < nIter; ++it) {
    const int b = it & 1;
    wait_vm0();
    __syncthreads();
    if (it + 1 < nIter) stage((it + 1) << 6, b ^ 1);

    long2v af[4], bfr[4];
#pragma unroll
    for (int i = 0; i < 4; ++i)
      af[i] = *(const long2v*)(&As[b][(wr + i * 16 + l15) * 64 + quad * 16]);
#pragma unroll
    for (int j = 0; j < 4; ++j)
      bfr[j] = *(const long2v*)(&Bs[b][(wc + j * 16 + l15) * 64 + quad * 16]);
#pragma unroll
    for (int i = 0; i < 4; ++i)
#pragma unroll
      for (int j = 0; j < 4; ++j) {
        acc[i][j] = __builtin_amdgcn_mfma_f32_16x16x32_fp8_fp8(af[i].x, bfr[j].x, acc[i][j], 0, 0, 0);
        acc[i][j] = __builtin_amdgcn_mfma_f32_16x16x32_fp8_fp8(af[i].y, bfr[j].y, acc[i][j], 0, 0, 0);
      }
  }

  const float scale = 0.044194173824159216f;  // 1/sqrt(512)
#pragma unroll
  for (int i = 0; i < 4; ++i) {
    const int rl = bm + wr + i * 16 + quad * 4;
#pragma unroll
    for (int r = 0; r < 4; ++r) {
      const int row = rl + r;
      float e[4];
#pragma unroll
      for (int j = 0; j < 4; ++j) {
        const int col = bn + wc + j * 16 + l15;
        const float lg = ((row0 + row) == col) ? 0.f : acc[i][j][r] * scale;
        e[j] = fminf(__expf(lg), 448.f);
      }
      // row-sum from fp32 values (fp8 num/denom inconsistency ~0.004% on l)
      float rsum = (e[0] + e[1]) + (e[2] + e[3]);
      const uint32_t d = gather_dword(pack4fp8(e), quad, l15);
      *(uint32_t*)(P8 + (size_t)row * Ncols + bn + wc + 4 * l15) = d;
      rsum += __shfl_xor(rsum, 1);
      rsum += __shfl_xor(rsum, 2);
      rsum += __shfl_xor(rsum, 4);
      rsum += __shfl_xor(rsum, 8);
      if (l15 == 0) atomicAdd(&lsum[row0 + row], rsum);
    }
  }
}

// ---------------------------------------------------------------------------
// PV GEMM, MX fp8 (r9 variant): O[m][n] = sum_k P8[m][k]*HbT8[n][k].
// 64x128 tile, BK=128, double-buffered, split-K over z. LDS 48KB -> 3 blk/CU.
// ---------------------------------------------------------------------------
template <bool DIRECT>
__global__ __launch_bounds__(256, 3) void gemm_pv8(
    const unsigned char* __restrict__ P,     // [rows][8192] fp8 (chunk base)
    const unsigned char* __restrict__ Bt,    // HbT8 [512][8192] fp8
    int Kchunk,
    const float* __restrict__ lvec,
    const float* __restrict__ Hres,
    int row0,
    float* __restrict__ outp,
    size_t partStride)
{
  __shared__ unsigned char As[2][64 * 128];   // 8 KiB x2
  __shared__ unsigned char Bs[2][128 * 128];  // 16 KiB x2

  const int tid  = threadIdx.x;
  const int lane = tid & 63;
  const int wave = tid >> 6;
  const int wr   = (wave >> 1) * 32;
  const int wc   = (wave & 1) * 64;
  const int quad = lane >> 4;
  const int l15  = lane & 15;
  const int bm   = blockIdx.y * 64;
  const int bn   = blockIdx.x * 128;
  const int k0   = blockIdx.z * Kchunk;

  float* part = outp + (DIRECT ? 0 : (size_t)blockIdx.z * partStride);

  // A: 512 chunks (64 rows x 128B); B: 1024 chunks (128 rows x 128B)
  const int a0 = tid, a1 = tid + 256;
  const int ar0 = a0 >> 3, ac0 = ((a0 & 7) ^ (ar0 & 7)) << 4;
  const int ar1 = a1 >> 3, ac1 = ((a1 & 7) ^ (ar1 & 7)) << 4;
  const int b0 = tid, b1 = tid + 256, b2 = tid + 512, b3 = tid + 768;
  const int br0 = b0 >> 3, bc0 = ((b0 & 7) ^ (br0 & 7)) << 4;
  const int br1 = b1 >> 3, bc1 = ((b1 & 7) ^ (br1 & 7)) << 4;
  const int br2 = b2 >> 3, bc2 = ((b2 & 7) ^ (br2 & 7)) << 4;
  const int br3 = b3 >> 3, bc3 = ((b3 & 7) ^ (br3 & 7)) << 4;

  auto stage = [&](int kt, int b) {
    __builtin_amdgcn_global_load_lds(
        (const GLOBAL_AS void*)(P + (size_t)(bm + ar0) * 8192 + kt + ac0),
        (LDS_AS void*)(&As[b][a0 * 16]), 16, 0, 0);
    __builtin_amdgcn_global_load_lds(
        (const GLOBAL_AS void*)(P + (size_t)(bm + ar1) * 8192 + kt + ac1),
        (LDS_AS void*)(&As[b][a1 * 16]), 16, 0, 0);
    __builtin_amdgcn_global_load_lds(
        (const GLOBAL_AS void*)(Bt + (size_t)(bn + br0) * 8192 + kt + bc0),
        (LDS_AS void*)(&Bs[b][b0 * 16]), 16, 0, 0);
    __builtin_amdgcn_global_load_lds(
        (const GLOBAL_AS void*)(Bt + (size_t)(bn + br1) * 8192 + kt + bc1),
        (LDS_AS void*)(&Bs[b][b1 * 16]), 16, 0, 0);
    __builtin_amdgcn_global_load_lds(
        (const GLOBAL_AS void*)(Bt + (size_t)(bn + br2) * 8192 + kt + bc2),
        (LDS_AS void*)(&Bs[b][b2 * 16]), 16, 0, 0);
    __builtin_amdgcn_global_load_lds(
        (const GLOBAL_AS void*)(Bt + (size_t)(bn + br3) * 8192 + kt + bc3),
        (LDS_AS void*)(&Bs[b][b3 * 16]), 16, 0, 0);
  };

  floatx4 acc[2][4];
#pragma unroll
  for (int i = 0; i < 2; ++i)
#pragma unroll
    for (int j = 0; j < 4; ++j)
      acc[i][j] = (floatx4){0.f, 0.f, 0.f, 0.f};

  stage(k0, 0);
  const int nIter = Kchunk >> 7;
  for (int it = 0; it < nIter; ++it) {
    const int b = it & 1;
    wait_vm0();
    __syncthreads();
    if (it + 1 < nIter) stage(k0 + ((it + 1) << 7), b ^ 1);

    const int8v af0 = load_frag32(As[b], wr + l15, quad);
    const int8v af1 = load_frag32(As[b], wr + 16 + l15, quad);
#pragma unroll
    for (int j = 0; j < 4; ++j) {
      const int8v bf = load_frag32(Bs[b], wc + j * 16 + l15, quad);
      acc[0][j] = mx_mfma(af0, bf, acc[0][j]);
      acc[1][j] = mx_mfma(af1, bf, acc[1][j]);
    }
  }

#pragma unroll
  for (int i = 0; i < 2; ++i) {
    const int rl = bm + wr + i * 16 + quad * 4;
#pragma unroll
    for (int j = 0; j < 4; ++j) {
      const int col = bn + wc + j * 16 + l15;
#pragma unroll
      for (int r = 0; r < 4; ++r) {
        const int row = rl + r;
        const float v = acc[i][j][r];
        if (DIRECT) {
          const int grow = row0 + row;
          part[(size_t)grow * 512 + col] =
              v / lvec[grow] + Hres[(size_t)grow * 512 + col];
        } else {
          part[(size_t)row * 512 + col] = v;
        }
      }
    }
  }
}

// combine: out = (sum_s partial_s) / l[row] + H
__global__ __launch_bounds__(256) void combine_kernel(
    const float* __restrict__ parts, size_t partStride, int S,
    const float* __restrict__ lvec, const float* __restrict__ Hres,
    float* __restrict__ out, int n4) {
  int i = blockIdx.x * 256 + threadIdx.x;
  if (i >= n4) return;
  float4 a = ((const float4*)parts)[i];
  for (int s = 1; s < S; ++s) {
    const float4 b = ((const float4*)(parts + (size_t)s * partStride))[i];
    a.x += b.x; a.y += b.y; a.z += b.z; a.w += b.w;
  }
  const int row = i >> 7;
  const float inv = 1.f / lvec[row];
  const float4 h = ((const float4*)Hres)[i];
  float4 o;
  o.x = a.x * inv + h.x;
  o.y = a.y * inv + h.y;
  o.z = a.z * inv + h.z;
  o.w = a.w * inv + h.w;
  ((float4*)out)[i] = o;
}

// ---------------------------------------------------------------------------
extern "C" void kernel_launch(void* const* d_in, const int* in_sizes, int n_in,
                              void* d_out, int out_size, void* d_ws, size_t ws_size,
                              hipStream_t stream) {
  const float* H  = (const float*)d_in[0];
  const float* Wq = (const float*)d_in[1];
  const float* bq = (const float*)d_in[2];
  const float* Wk = (const float*)d_in[3];
  const float* bk = (const float*)d_in[4];
  float* out = (float*)d_out;

  const int N = 8192, D = 512;

  char* ws = (char*)d_ws;
  size_t off = 0;
  auto alloc = [&](size_t bytes) { char* p = ws + off; off += bytes; return p; };
  unsigned short* Hb   = (unsigned short*)alloc((size_t)N * D * 2);       // 8 MB
  unsigned char*  HbT8 = (unsigned char*)alloc((size_t)D * N);            // 4.2 MB
  unsigned char*  QK8  = (unsigned char*)alloc((size_t)N * 2 * D);        // 8.4 MB
  unsigned short* BqkT = (unsigned short*)alloc((size_t)2 * D * D * 2);   // 1 MB
  float* bqk = (float*)alloc((size_t)2 * D * 4);
  float* l   = (float*)alloc((size_t)N * 4);
  const size_t base = off;
  unsigned char* P8 = (unsigned char*)(ws + base);

  const size_t pBytes = (size_t)N * N;                   // 67 MB (fp8)
  const size_t partBytes = (size_t)N * D * 4;            // 16.8 MB each
  const size_t partStride = (size_t)N * D;               // floats
  const size_t avail = (ws_size > base) ? (ws_size - base) : 0;

  int S = 0;
  if (avail >= pBytes) {
    const size_t extra = avail - pBytes;
    S = (extra >= 2 * partBytes) ? 2 : 1;
  }
  float* parts = (float*)(ws + base + pBytes);

  // --- prep ---
  hipMemsetAsync(l, 0, (size_t)N * 4, stream);
  transpose_h_kernel<<<dim3(D / 64, N / 64), 256, 0, stream>>>(H, HbT8, Hb, N, D);
  transpose_w_kernel<<<dim3(D / 64, D / 64), 256, 0, stream>>>(Wq, BqkT, D, D);
  transpose_w_kernel<<<dim3(D / 64, D / 64), 256, 0, stream>>>(Wk, BqkT + (size_t)D * D, D, D);
  pack_bias_kernel<<<dim3(4), 256, 0, stream>>>(bq, bk, bqk);

  // --- merged Q|K projection -> fp8: QK8[8192][1024] ---
  gemm_proj<<<dim3(2 * D / 128, N / 128), 256, 0, stream>>>(
      Hb, BqkT, 2 * D, D, bqk, QK8);

  if (S >= 1) {
    // scores: P8 = fp8(exp(diag0(Q K^T)*scale)), fused row-sums into l
    gemm_qk8<<<dim3(N / 128, N / 128), 256, 0, stream>>>(
        QK8, QK8 + D, N, D, 2 * D, 2 * D, l, 0, P8);
    if (S == 1) {
      gemm_pv8<true><<<dim3(D / 128, N / 64, 1), 256, 0, stream>>>(
          P8, HbT8, N, l, H, 0, out, 0);
    } else {
      gemm_pv8<false><<<dim3(D / 128, N / 64, S), 256, 0, stream>>>(
          P8, HbT8, N / S, nullptr, nullptr, 0, parts, partStride);
      combine_kernel<<<dim3((N * D / 4 + 255) / 256), 256, 0, stream>>>(
          parts, partStride, S, l, H, out, N * D / 4);
    }
  } else {
    // ws too small for full P8: chunk rows (direct PV per chunk)
    int maxRows = (int)(avail / (size_t)N);
    maxRows &= ~127;
    if (maxRows < 128) maxRows = 128;
    for (int r0 = 0; r0 < N; r0 += maxRows) {
      int rows = N - r0;
      if (rows > maxRows) rows = maxRows;
      gemm_qk8<<<dim3(N / 128, rows / 128), 256, 0, stream>>>(
          QK8 + (size_t)r0 * 2 * D, QK8 + D, N, D, 2 * D, 2 * D, l, r0, P8);
      gemm_pv8<true><<<dim3(D / 128, rows / 64, 1), 256, 0, stream>>>(
          P8, HbT8, N, l, H, r0, out, 0);
    }
  }
}